// Round 14
// baseline (4587.055 us; speedup 1.0000x reference)
//
#include <hip/hip_runtime.h>
#include <hip/hip_bf16.h>
#include <math.h>

// Problem constants
#define NN 50000
#define NNP 50048       // rows padded to multiple of 128
#define NE 800000
#define DD 256
#define NSTEPS 6

#define BK 32

typedef unsigned short u16;
typedef _Float16 f16x8 __attribute__((ext_vector_type(8)));
typedef _Float16 f16x4 __attribute__((ext_vector_type(4)));
typedef float f32x4 __attribute__((ext_vector_type(4)));

__device__ __forceinline__ float sigmoidf_(float v) {
    return 1.0f / (1.0f + expf(-v));
}
__device__ __forceinline__ u16 f2h(float v) {
    _Float16 h = (_Float16)v;            // RNE
    u16 u; __builtin_memcpy(&u, &h, 2); return u;
}
__device__ __forceinline__ float h2f(u16 u) {
    _Float16 h; __builtin_memcpy(&h, &u, 2); return (float)h;
}
// fp16 2-way split: v ~= h + l to 2^-22 relative
__device__ __forceinline__ void split2(float v, u16& h, u16& l) {
    h = f2h(v);
    float r = v - h2f(h);
    l = f2h(r);
}
__device__ __forceinline__ unsigned pk(u16 a, u16 b) {
    return (unsigned)a | ((unsigned)b << 16);
}
__device__ __forceinline__ void store_planes(u16* base, size_t ps, size_t off, float v) {
    u16 h, l; split2(v, h, l);
    base[off] = h; base[ps + off] = l;
}
__device__ __forceinline__ void gload16(const void* g, void* l) {
    __builtin_amdgcn_global_load_lds(
        (const __attribute__((address_space(1))) void*)g,
        (__attribute__((address_space(3))) void*)l, 16, 0, 0);
}

// ---------------- CSR build (verified R1-R13) ----------------

__global__ void zero_kernel(int* __restrict__ p, int n) {
    int i = blockIdx.x * blockDim.x + threadIdx.x;
    if (i < n) p[i] = 0;
}
__global__ void hist_kernel(const int* __restrict__ dst, int* __restrict__ counts, int E) {
    int e = blockIdx.x * blockDim.x + threadIdx.x;
    if (e < E) atomicAdd(&counts[dst[e]], 1);
}
__global__ void scan_kernel(const int* __restrict__ counts, int* __restrict__ row_ptr, int n) {
    __shared__ int buf[1024];
    __shared__ int carry;
    const int tid = threadIdx.x;
    if (tid == 0) carry = 0;
    __syncthreads();
    for (int base = 0; base < n; base += 1024) {
        int i = base + tid;
        int v = (i < n) ? counts[i] : 0;
        buf[tid] = v;
        __syncthreads();
        for (int off = 1; off < 1024; off <<= 1) {
            int t = (tid >= off) ? buf[tid - off] : 0;
            __syncthreads();
            buf[tid] += t;
            __syncthreads();
        }
        if (i < n) row_ptr[i] = carry + buf[tid] - v;
        __syncthreads();
        if (tid == 0) carry += buf[1023];
        __syncthreads();
    }
    if (threadIdx.x == 0) row_ptr[n] = carry;
}
__global__ void fill_kernel(const int* __restrict__ src, const int* __restrict__ dst,
                            const int* __restrict__ row_ptr, int* __restrict__ cursor,
                            int* __restrict__ csr_src, int E) {
    int e = blockIdx.x * blockDim.x + threadIdx.x;
    if (e < E) {
        int d = dst[e];
        int p = atomicAdd(&cursor[d], 1);
        csr_src[row_ptr[d] + p] = src[e];
    }
}

// ---------------- fp32 -> 2 fp16 planes (rows padded w/ zero) ----------------
__global__ void split_rows(const float* __restrict__ src, u16* __restrict__ dst,
                           size_t pstride, int srcRows) {
    int row = blockIdx.x;
    int col = threadIdx.x;
    size_t off = (size_t)row * DD + col;
    float v = (row < srcRows) ? src[off] : 0.0f;
    store_planes(dst, pstride, off, v);
}

// ---------------- fused MLP (R13-verified) ----------------
__global__ __launch_bounds__(256, 3)
void mlp_fused(const u16* __restrict__ pX, size_t psA,
               const u16* __restrict__ W1P, const u16* __restrict__ W2P, size_t psW,
               const float* __restrict__ b1, const float* __restrict__ b2,
               u16* __restrict__ HP, int M) {
    __shared__ u16 lds[26624];
    const int T1B = 18432;

    const int tid = threadIdx.x;
    const int lane = tid & 63;
    const int wv = tid >> 6;           // col quarter 0..3
    const int frow = lane & 15;
    const int kg = lane >> 4;
    const int rowBase = blockIdx.x * 32;

    int offj[9]; int ldsj[9]; bool isWj[9];
#pragma unroll
    for (int j = 0; j < 9; ++j) {
        int q = wv * 9 + j;
        int row, plane, ldso;
        bool isW = q >= 4;
        if (!isW) {
            plane = q >> 1; int sub = q & 1;
            row = sub * 16 + (lane >> 2);
            ldso = q * 512;
        } else {
            int qw = q - 4;
            plane = qw >> 4; int sub = qw & 15;
            row = sub * 16 + (lane >> 2);
            ldso = 2048 + qw * 512;
        }
        int chunk = (lane & 3) ^ ((row >> 1) & 3);
        offj[j] = plane * (int)(isW ? psW : psA) + ((isW ? 0 : rowBase) + row) * DD + chunk * 8;
        ldsj[j] = ldso;
        isWj[j] = isW;
    }

    // phase 1: t1 = ReLU(x @ W1^T + b1)
    f32x4 acc1[2][4] = {};
    for (int kc = 0; kc < DD; kc += BK) {
#pragma unroll
        for (int j = 0; j < 9; ++j)
            gload16((isWj[j] ? W1P : pX) + offj[j] + kc, &lds[ldsj[j]]);
        __syncthreads();

        f16x8 af[2][2];
#pragma unroll
        for (int mf = 0; mf < 2; ++mf) {
            int row = mf * 16 + frow;
            int off = row * 32 + ((kg ^ ((row >> 1) & 3)) * 8);
            af[0][mf] = *reinterpret_cast<const f16x8*>(&lds[off]);
            af[1][mf] = *reinterpret_cast<const f16x8*>(&lds[1024 + off]);
        }
#pragma unroll
        for (int nf = 0; nf < 4; ++nf) {
            int brow = wv * 64 + nf * 16 + frow;
            int boff = 2048 + brow * 32 + ((kg ^ ((brow >> 1) & 3)) * 8);
            f16x8 bh = *reinterpret_cast<const f16x8*>(&lds[boff]);
            f16x8 bl = *reinterpret_cast<const f16x8*>(&lds[boff + 8192]);
#pragma unroll
            for (int mf = 0; mf < 2; ++mf) {
                f32x4 c = acc1[mf][nf];
                c = __builtin_amdgcn_mfma_f32_16x16x32_f16(af[0][mf], bh, c, 0, 0, 0);
                c = __builtin_amdgcn_mfma_f32_16x16x32_f16(af[0][mf], bl, c, 0, 0, 0);
                c = __builtin_amdgcn_mfma_f32_16x16x32_f16(af[1][mf], bh, c, 0, 0, 0);
                acc1[mf][nf] = c;
            }
        }
        __syncthreads();
    }

    // t1 -> LDS fp16 (swizzled)
#pragma unroll
    for (int nf = 0; nf < 4; ++nf) {
        int col = wv * 64 + nf * 16 + frow;
        float bb = b1[col];
        int c8 = col >> 3, ci = col & 7;
#pragma unroll
        for (int mf = 0; mf < 2; ++mf) {
#pragma unroll
            for (int j = 0; j < 4; ++j) {
                int row = mf * 16 + kg * 4 + j;
                float v = fmaxf(acc1[mf][nf][j] + bb, 0.0f);
                lds[T1B + row * 256 + ((c8 ^ (row & 7)) * 8) + ci] = f2h(v);
            }
        }
    }
    __syncthreads();

    // phase 2: h = t1 @ W2^T + b2
    f32x4 acc2[2][4] = {};
    for (int kc = 0; kc < DD; kc += BK) {
#pragma unroll
        for (int j = 0; j < 9; ++j)
            if (isWj[j]) gload16(W2P + offj[j] + kc, &lds[ldsj[j]]);
        __syncthreads();

        f16x8 at[2];
#pragma unroll
        for (int mf = 0; mf < 2; ++mf) {
            int row = mf * 16 + frow;
            int qc = (kc >> 3) + kg;
            at[mf] = *reinterpret_cast<const f16x8*>(
                &lds[T1B + row * 256 + ((qc ^ (row & 7)) * 8)]);
        }
#pragma unroll
        for (int nf = 0; nf < 4; ++nf) {
            int brow = wv * 64 + nf * 16 + frow;
            int boff = 2048 + brow * 32 + ((kg ^ ((brow >> 1) & 3)) * 8);
            f16x8 bh = *reinterpret_cast<const f16x8*>(&lds[boff]);
            f16x8 bl = *reinterpret_cast<const f16x8*>(&lds[boff + 8192]);
#pragma unroll
            for (int mf = 0; mf < 2; ++mf) {
                f32x4 c = acc2[mf][nf];
                c = __builtin_amdgcn_mfma_f32_16x16x32_f16(at[mf], bh, c, 0, 0, 0);
                c = __builtin_amdgcn_mfma_f32_16x16x32_f16(at[mf], bl, c, 0, 0, 0);
                acc2[mf][nf] = c;
            }
        }
        __syncthreads();
    }

#pragma unroll
    for (int nf = 0; nf < 4; ++nf) {
        int col = wv * 64 + nf * 16 + frow;
        float bb = b2[col];
#pragma unroll
        for (int mf = 0; mf < 2; ++mf) {
#pragma unroll
            for (int j = 0; j < 4; ++j) {
                int gr = rowBase + mf * 16 + kg * 4 + j;
                if (gr < M) HP[(size_t)gr * DD + col] = f2h(acc2[mf][nf][j] + bb);
            }
        }
    }
}

// ---------------- fused GRU: 256-thread blocks, 4 blocks/CU ----------------
// BM=64 rows, BN=128 cols, grid (NNP/64, 2). Wave wv = col quarter (32 cols).
// r,z gates: 2-term product (hh + lh; drops A_hi x B_lo ~ 2^-11) -> no B-lo
// staging for r,z. n gate: full 3-term. LDS 40 KB -> 4 blocks/CU (4 independent
// barrier groups vs R13's 2 -> latency hiding via block-level TLP).
template <bool FINAL>
__global__ __launch_bounds__(256, 4)
void gru_fused(const u16* __restrict__ pMsg, const u16* __restrict__ pX, size_t psA,
               const u16* __restrict__ pWih, const u16* __restrict__ pWhh, size_t psB,
               const float* __restrict__ bih, const float* __restrict__ bhh,
               float* __restrict__ outF, u16* __restrict__ outP, size_t psO, int M) {
    // LDS (u16): A-hi [64][32] at 0, A-lo at 2048;
    // B planes [128][32]: r-hi 4096, z-hi 8192, n-hi 12288, n-lo 16384. 40 KB.
    __shared__ u16 lds[20480];

    const int tid = threadIdx.x;
    const int lane = tid & 63;
    const int wv = tid >> 6;           // col quarter 0..3
    const int frow = lane & 15;
    const int kg = lane >> 4;
    const int rowBase = blockIdx.x * 64;
    const int colBase = blockIdx.y * 128;

    // staging: 40 x 1KB issues per k-iter, 10 per wave.
    // q = wv*10+j; q<8: A (plane q>>2, sub q&3); q>=8: qb=q-8: B plane qb>>3
    // (0=r-hi,1=z-hi,2=n-hi,3=n-lo), sub qb&7.
    int offj[10]; int ldsj[10]; bool isBj[10];
#pragma unroll
    for (int j = 0; j < 10; ++j) {
        int q = wv * 10 + j;
        bool isB = q >= 8;
        int eoff, ldso;
        if (!isB) {
            int p = q >> 2; int sub = q & 3;
            int row = sub * 16 + (lane >> 2);
            int chunk = (lane & 3) ^ ((row >> 1) & 3);
            eoff = p * (int)psA + (rowBase + row) * DD + chunk * 8;
            ldso = q * 512;
        } else {
            int qb = q - 8;                  // 0..31
            int bp = qb >> 3;                // 0:r-hi 1:z-hi 2:n-hi 3:n-lo
            int sub = qb & 7;
            int row = sub * 16 + (lane >> 2);
            int chunk = (lane & 3) ^ ((row >> 1) & 3);
            int gate = (bp < 2) ? bp : 2;    // weight row block
            int p = (bp == 3) ? 1 : 0;       // plane (lo only for n)
            eoff = p * (int)psB + (gate * 256 + colBase + row) * DD + chunk * 8;
            ldso = 4096 + qb * 512;
        }
        offj[j] = eoff; ldsj[j] = ldso; isBj[j] = isB;
    }

    f32x4 accr[4][2] = {};
    f32x4 accz[4][2] = {};
    f32x4 accx[4][2] = {};
    f32x4 acch[4][2] = {};

#pragma unroll
    for (int half = 0; half < 2; ++half) {
        const u16* Ab = half ? pX : pMsg;
        const u16* Bb = half ? pWhh : pWih;
        for (int kc = 0; kc < DD; kc += BK) {
#pragma unroll
            for (int j = 0; j < 10; ++j)
                gload16((isBj[j] ? Bb : Ab) + offj[j] + kc, &lds[ldsj[j]]);
            __syncthreads();

            f16x8 af[2][4];
#pragma unroll
            for (int mf = 0; mf < 4; ++mf) {
                int row = mf * 16 + frow;
                int off = row * 32 + ((kg ^ ((row >> 1) & 3)) * 8);
                af[0][mf] = *reinterpret_cast<const f16x8*>(&lds[off]);
                af[1][mf] = *reinterpret_cast<const f16x8*>(&lds[2048 + off]);
            }
#pragma unroll
            for (int nf = 0; nf < 2; ++nf) {
                int brow = wv * 32 + nf * 16 + frow;
                int bsw = (kg ^ ((brow >> 1) & 3)) * 8;
                f16x8 brh = *reinterpret_cast<const f16x8*>(&lds[4096 + brow * 32 + bsw]);
                f16x8 bzh = *reinterpret_cast<const f16x8*>(&lds[8192 + brow * 32 + bsw]);
                f16x8 bnh = *reinterpret_cast<const f16x8*>(&lds[12288 + brow * 32 + bsw]);
                f16x8 bnl = *reinterpret_cast<const f16x8*>(&lds[16384 + brow * 32 + bsw]);
#pragma unroll
                for (int mf = 0; mf < 4; ++mf) {
                    // r gate: hh + lh
                    f32x4 cr = accr[mf][nf];
                    cr = __builtin_amdgcn_mfma_f32_16x16x32_f16(af[0][mf], brh, cr, 0, 0, 0);
                    cr = __builtin_amdgcn_mfma_f32_16x16x32_f16(af[1][mf], brh, cr, 0, 0, 0);
                    accr[mf][nf] = cr;
                    // z gate: hh + lh
                    f32x4 cz = accz[mf][nf];
                    cz = __builtin_amdgcn_mfma_f32_16x16x32_f16(af[0][mf], bzh, cz, 0, 0, 0);
                    cz = __builtin_amdgcn_mfma_f32_16x16x32_f16(af[1][mf], bzh, cz, 0, 0, 0);
                    accz[mf][nf] = cz;
                    // n gate: hh + hl + lh
                    f32x4 cn = (half == 0) ? accx[mf][nf] : acch[mf][nf];
                    cn = __builtin_amdgcn_mfma_f32_16x16x32_f16(af[0][mf], bnh, cn, 0, 0, 0);
                    cn = __builtin_amdgcn_mfma_f32_16x16x32_f16(af[0][mf], bnl, cn, 0, 0, 0);
                    cn = __builtin_amdgcn_mfma_f32_16x16x32_f16(af[1][mf], bnh, cn, 0, 0, 0);
                    if (half == 0) accx[mf][nf] = cn; else acch[mf][nf] = cn;
                }
            }
            __syncthreads();
        }
    }

    // epilogue: full GRU update
#pragma unroll
    for (int nf = 0; nf < 2; ++nf) {
        int gc = colBase + wv * 32 + nf * 16 + frow;
        float br = bih[gc] + bhh[gc];
        float bz = bih[256 + gc] + bhh[256 + gc];
        float bx = bih[512 + gc];
        float bh = bhh[512 + gc];
#pragma unroll
        for (int mf = 0; mf < 4; ++mf) {
#pragma unroll
            for (int j = 0; j < 4; ++j) {
                int gr = rowBase + mf * 16 + kg * 4 + j;
                if (gr < M) {
                    size_t off = (size_t)gr * DD + gc;
                    float r = sigmoidf_(accr[mf][nf][j] + br);
                    float z = sigmoidf_(accz[mf][nf][j] + bz);
                    float T = tanhf(accx[mf][nf][j] + bx + r * (acch[mf][nf][j] + bh));
                    float x = h2f(pX[off]) + h2f(pX[psA + off]);
                    float o = (1.0f - z) * T + z * x;
                    if (FINAL) outF[off] = o;
                    else       store_planes(outP, psO, off, o);
                }
            }
        }
    }
}

// ---------------- segment sum (gather over fp16 h table) -> msg planes ----------------
__global__ __launch_bounds__(256)
void segsum_kernel(const u16* __restrict__ hp, const int* __restrict__ row_ptr,
                   const int* __restrict__ csr_src, u16* __restrict__ msgP,
                   size_t ps, int n) {
    int node = blockIdx.x * 4 + threadIdx.y;
    if (node >= n) return;
    int d4 = threadIdx.x * 4;
    int s = row_ptr[node];
    int e = row_ptr[node + 1];
    float4 acc = make_float4(0.f, 0.f, 0.f, 0.f);
    for (int j = s; j < e; ++j) {
        int sn = csr_src[j];
        f16x4 v = *reinterpret_cast<const f16x4*>(&hp[(size_t)sn * DD + d4]);
        acc.x += (float)v[0]; acc.y += (float)v[1];
        acc.z += (float)v[2]; acc.w += (float)v[3];
    }
    size_t off = (size_t)node * DD + d4;
    u16 h0,l0,h1,l1,h2,l2,h3,l3;
    split2(acc.x, h0,l0); split2(acc.y, h1,l1);
    split2(acc.z, h2,l2); split2(acc.w, h3,l3);
    *reinterpret_cast<uint2*>(&msgP[off])      = make_uint2(pk(h0,h1), pk(h2,h3));
    *reinterpret_cast<uint2*>(&msgP[ps + off]) = make_uint2(pk(l0,l1), pk(l2,l3));
}

// ---------------- launch ----------------

extern "C" void kernel_launch(void* const* d_in, const int* in_sizes, int n_in,
                              void* d_out, int out_size, void* d_ws, size_t ws_size,
                              hipStream_t stream) {
    const float* x0  = (const float*)d_in[0];
    const float* W1  = (const float*)d_in[1];
    const float* b1  = (const float*)d_in[2];
    const float* W2  = (const float*)d_in[3];
    const float* b2  = (const float*)d_in[4];
    const float* Wih = (const float*)d_in[5];
    const float* bih = (const float*)d_in[6];
    const float* Whh = (const float*)d_in[7];
    const float* bhh = (const float*)d_in[8];
    const int*   src = (const int*)d_in[9];
    const int*   dst = (const int*)d_in[10];

    // workspace layout (~211.3 MB — proven footprint)
    char* ws = (char*)d_ws;
    const size_t PSA = (size_t)NNP * DD;
    const size_t SP  = PSA * 2 * sizeof(u16);
    const size_t NB  = PSA * sizeof(float);
    const size_t PSW2 = (size_t)DD * DD;
    const size_t PSW3 = (size_t)3 * DD * DD;
    u16* XP0   = (u16*)(ws);
    u16* XP1   = (u16*)(ws + SP);
    u16* TP    = (u16*)(ws + 2 * SP);
    u16* HP    = (u16*)(ws + 3 * SP);
    u16* W1P   = (u16*)(ws + 3 * SP + NB);
    u16* W2P   = W1P + 2 * PSW2;
    u16* WIHP  = W2P + 2 * PSW2;
    u16* WHHP  = WIHP + 2 * PSW3;
    int* counts  = (int*)(WHHP + 2 * PSW3);
    int* cursor  = counts + NN;
    int* row_ptr = cursor + NN;
    int* csr     = row_ptr + NN + 8;
    const size_t needed = 3 * SP + NB + (4 * PSW2 + 4 * PSW3) * sizeof(u16)
                        + (size_t)(2 * NN + NN + 9 + NE) * sizeof(int);
    if (ws_size < needed) return;

    float* FOUT = (float*)d_out;

    // CSR build
    zero_kernel<<<(2 * NN + 255) / 256, 256, 0, stream>>>(counts, 2 * NN);
    hist_kernel<<<(NE + 255) / 256, 256, 0, stream>>>(dst, counts, NE);
    scan_kernel<<<1, 1024, 0, stream>>>(counts, row_ptr, NN);
    fill_kernel<<<(NE + 255) / 256, 256, 0, stream>>>(src, dst, row_ptr, cursor, csr, NE);

    // pre-split weights (once) and x0 -> XP0
    split_rows<<<DD, 256, 0, stream>>>(W1, W1P, PSW2, DD);
    split_rows<<<DD, 256, 0, stream>>>(W2, W2P, PSW2, DD);
    split_rows<<<3 * DD, 256, 0, stream>>>(Wih, WIHP, PSW3, 3 * DD);
    split_rows<<<3 * DD, 256, 0, stream>>>(Whh, WHHP, PSW3, 3 * DD);
    split_rows<<<NNP, 256, 0, stream>>>(x0, XP0, PSA, NN);

    const dim3 gridGRU(NNP / 64, 2);   // 782 x 2, 256-thread blocks

    for (int s = 0; s < NSTEPS; ++s) {
        u16* XPc = (s & 1) ? XP1 : XP0;
        u16* XPn = (s & 1) ? XP0 : XP1;

        // h = MLP(x) -> HP (single fp16 plane), t1 never touches HBM
        mlp_fused<<<NNP / 32, 256, 0, stream>>>(
            XPc, PSA, W1P, W2P, PSW2, b1, b2, HP, NN);
        // msg = segment_sum(h[src], dst) -> TP planes
        segsum_kernel<<<dim3((NN + 3) / 4), dim3(64, 4), 0, stream>>>(
            HP, row_ptr, csr, TP, PSA, NN);
        // full GRU update -> x_next planes (final: fp32 d_out)
        if (s < NSTEPS - 1) {
            gru_fused<false><<<gridGRU, 256, 0, stream>>>(
                TP, XPc, PSA, WIHP, WHHP, PSW3, bih, bhh,
                nullptr, XPn, PSA, NN);
        } else {
            gru_fused<true><<<gridGRU, 256, 0, stream>>>(
                TP, XPc, PSA, WIHP, WHHP, PSW3, bih, bhh,
                FOUT, nullptr, 0, NN);
        }
    }
}

// Round 15
// 2200.114 us; speedup vs baseline: 2.0849x; 2.0849x over previous
//
#include <hip/hip_runtime.h>
#include <hip/hip_bf16.h>
#include <math.h>

// Problem constants
#define NN 50000
#define NNP 50048       // rows padded to multiple of 128
#define NE 800000
#define DD 256
#define NSTEPS 6

#define BK 32

typedef unsigned short u16;
typedef _Float16 f16x8 __attribute__((ext_vector_type(8)));
typedef _Float16 f16x4 __attribute__((ext_vector_type(4)));
typedef float f32x4 __attribute__((ext_vector_type(4)));

__device__ __forceinline__ float sigmoidf_(float v) {
    return 1.0f / (1.0f + expf(-v));
}
__device__ __forceinline__ u16 f2h(float v) {
    _Float16 h = (_Float16)v;            // RNE
    u16 u; __builtin_memcpy(&u, &h, 2); return u;
}
__device__ __forceinline__ float h2f(u16 u) {
    _Float16 h; __builtin_memcpy(&h, &u, 2); return (float)h;
}
// fp16 2-way split: v ~= h + l to 2^-22 relative
__device__ __forceinline__ void split2(float v, u16& h, u16& l) {
    h = f2h(v);
    float r = v - h2f(h);
    l = f2h(r);
}
__device__ __forceinline__ unsigned pk(u16 a, u16 b) {
    return (unsigned)a | ((unsigned)b << 16);
}
__device__ __forceinline__ void store_planes(u16* base, size_t ps, size_t off, float v) {
    u16 h, l; split2(v, h, l);
    base[off] = h; base[ps + off] = l;
}
__device__ __forceinline__ void gload16(const void* g, void* l) {
    __builtin_amdgcn_global_load_lds(
        (const __attribute__((address_space(1))) void*)g,
        (__attribute__((address_space(3))) void*)l, 16, 0, 0);
}

// ---------------- CSR build (verified R1-R14) ----------------

__global__ void zero_kernel(int* __restrict__ p, int n) {
    int i = blockIdx.x * blockDim.x + threadIdx.x;
    if (i < n) p[i] = 0;
}
__global__ void hist_kernel(const int* __restrict__ dst, int* __restrict__ counts, int E) {
    int e = blockIdx.x * blockDim.x + threadIdx.x;
    if (e < E) atomicAdd(&counts[dst[e]], 1);
}
__global__ void scan_kernel(const int* __restrict__ counts, int* __restrict__ row_ptr, int n) {
    __shared__ int buf[1024];
    __shared__ int carry;
    const int tid = threadIdx.x;
    if (tid == 0) carry = 0;
    __syncthreads();
    for (int base = 0; base < n; base += 1024) {
        int i = base + tid;
        int v = (i < n) ? counts[i] : 0;
        buf[tid] = v;
        __syncthreads();
        for (int off = 1; off < 1024; off <<= 1) {
            int t = (tid >= off) ? buf[tid - off] : 0;
            __syncthreads();
            buf[tid] += t;
            __syncthreads();
        }
        if (i < n) row_ptr[i] = carry + buf[tid] - v;
        __syncthreads();
        if (tid == 0) carry += buf[1023];
        __syncthreads();
    }
    if (threadIdx.x == 0) row_ptr[n] = carry;
}
__global__ void fill_kernel(const int* __restrict__ src, const int* __restrict__ dst,
                            const int* __restrict__ row_ptr, int* __restrict__ cursor,
                            int* __restrict__ csr_src, int E) {
    int e = blockIdx.x * blockDim.x + threadIdx.x;
    if (e < E) {
        int d = dst[e];
        int p = atomicAdd(&cursor[d], 1);
        csr_src[row_ptr[d] + p] = src[e];
    }
}

// ---------------- fp32 -> 2 fp16 planes (rows padded w/ zero) ----------------
__global__ void split_rows(const float* __restrict__ src, u16* __restrict__ dst,
                           size_t pstride, int srcRows) {
    int row = blockIdx.x;
    int col = threadIdx.x;
    size_t off = (size_t)row * DD + col;
    float v = (row < srcRows) ? src[off] : 0.0f;
    store_planes(dst, pstride, off, v);
}

// ---------------- fused MLP (R13-verified) ----------------
__global__ __launch_bounds__(256, 3)
void mlp_fused(const u16* __restrict__ pX, size_t psA,
               const u16* __restrict__ W1P, const u16* __restrict__ W2P, size_t psW,
               const float* __restrict__ b1, const float* __restrict__ b2,
               u16* __restrict__ HP, int M) {
    __shared__ u16 lds[26624];
    const int T1B = 18432;

    const int tid = threadIdx.x;
    const int lane = tid & 63;
    const int wv = tid >> 6;           // col quarter 0..3
    const int frow = lane & 15;
    const int kg = lane >> 4;
    const int rowBase = blockIdx.x * 32;

    int offj[9]; int ldsj[9]; bool isWj[9];
#pragma unroll
    for (int j = 0; j < 9; ++j) {
        int q = wv * 9 + j;
        int row, plane, ldso;
        bool isW = q >= 4;
        if (!isW) {
            plane = q >> 1; int sub = q & 1;
            row = sub * 16 + (lane >> 2);
            ldso = q * 512;
        } else {
            int qw = q - 4;
            plane = qw >> 4; int sub = qw & 15;
            row = sub * 16 + (lane >> 2);
            ldso = 2048 + qw * 512;
        }
        int chunk = (lane & 3) ^ ((row >> 1) & 3);
        offj[j] = plane * (int)(isW ? psW : psA) + ((isW ? 0 : rowBase) + row) * DD + chunk * 8;
        ldsj[j] = ldso;
        isWj[j] = isW;
    }

    // phase 1: t1 = ReLU(x @ W1^T + b1)
    f32x4 acc1[2][4] = {};
    for (int kc = 0; kc < DD; kc += BK) {
#pragma unroll
        for (int j = 0; j < 9; ++j)
            gload16((isWj[j] ? W1P : pX) + offj[j] + kc, &lds[ldsj[j]]);
        __syncthreads();

        f16x8 af[2][2];
#pragma unroll
        for (int mf = 0; mf < 2; ++mf) {
            int row = mf * 16 + frow;
            int off = row * 32 + ((kg ^ ((row >> 1) & 3)) * 8);
            af[0][mf] = *reinterpret_cast<const f16x8*>(&lds[off]);
            af[1][mf] = *reinterpret_cast<const f16x8*>(&lds[1024 + off]);
        }
#pragma unroll
        for (int nf = 0; nf < 4; ++nf) {
            int brow = wv * 64 + nf * 16 + frow;
            int boff = 2048 + brow * 32 + ((kg ^ ((brow >> 1) & 3)) * 8);
            f16x8 bh = *reinterpret_cast<const f16x8*>(&lds[boff]);
            f16x8 bl = *reinterpret_cast<const f16x8*>(&lds[boff + 8192]);
#pragma unroll
            for (int mf = 0; mf < 2; ++mf) {
                f32x4 c = acc1[mf][nf];
                c = __builtin_amdgcn_mfma_f32_16x16x32_f16(af[0][mf], bh, c, 0, 0, 0);
                c = __builtin_amdgcn_mfma_f32_16x16x32_f16(af[0][mf], bl, c, 0, 0, 0);
                c = __builtin_amdgcn_mfma_f32_16x16x32_f16(af[1][mf], bh, c, 0, 0, 0);
                acc1[mf][nf] = c;
            }
        }
        __syncthreads();
    }

    // t1 -> LDS fp16 (swizzled)
#pragma unroll
    for (int nf = 0; nf < 4; ++nf) {
        int col = wv * 64 + nf * 16 + frow;
        float bb = b1[col];
        int c8 = col >> 3, ci = col & 7;
#pragma unroll
        for (int mf = 0; mf < 2; ++mf) {
#pragma unroll
            for (int j = 0; j < 4; ++j) {
                int row = mf * 16 + kg * 4 + j;
                float v = fmaxf(acc1[mf][nf][j] + bb, 0.0f);
                lds[T1B + row * 256 + ((c8 ^ (row & 7)) * 8) + ci] = f2h(v);
            }
        }
    }
    __syncthreads();

    // phase 2: h = t1 @ W2^T + b2
    f32x4 acc2[2][4] = {};
    for (int kc = 0; kc < DD; kc += BK) {
#pragma unroll
        for (int j = 0; j < 9; ++j)
            if (isWj[j]) gload16(W2P + offj[j] + kc, &lds[ldsj[j]]);
        __syncthreads();

        f16x8 at[2];
#pragma unroll
        for (int mf = 0; mf < 2; ++mf) {
            int row = mf * 16 + frow;
            int qc = (kc >> 3) + kg;
            at[mf] = *reinterpret_cast<const f16x8*>(
                &lds[T1B + row * 256 + ((qc ^ (row & 7)) * 8)]);
        }
#pragma unroll
        for (int nf = 0; nf < 4; ++nf) {
            int brow = wv * 64 + nf * 16 + frow;
            int boff = 2048 + brow * 32 + ((kg ^ ((brow >> 1) & 3)) * 8);
            f16x8 bh = *reinterpret_cast<const f16x8*>(&lds[boff]);
            f16x8 bl = *reinterpret_cast<const f16x8*>(&lds[boff + 8192]);
#pragma unroll
            for (int mf = 0; mf < 2; ++mf) {
                f32x4 c = acc2[mf][nf];
                c = __builtin_amdgcn_mfma_f32_16x16x32_f16(at[mf], bh, c, 0, 0, 0);
                c = __builtin_amdgcn_mfma_f32_16x16x32_f16(at[mf], bl, c, 0, 0, 0);
                acc2[mf][nf] = c;
            }
        }
        __syncthreads();
    }

#pragma unroll
    for (int nf = 0; nf < 4; ++nf) {
        int col = wv * 64 + nf * 16 + frow;
        float bb = b2[col];
#pragma unroll
        for (int mf = 0; mf < 2; ++mf) {
#pragma unroll
            for (int j = 0; j < 4; ++j) {
                int gr = rowBase + mf * 16 + kg * 4 + j;
                if (gr < M) HP[(size_t)gr * DD + col] = f2h(acc2[mf][nf][j] + bb);
            }
        }
    }
}

// ---------------- fused GRU (R13 512-thread structure + 2-term r,z gates) ----------------
// r,z: hh + lh (drops A_hi x B_lo ~ 2^-11; validated absmax 0.0234 in R14).
// n: full 3-term. B staging 4 planes (r-hi, z-hi, n-hi, n-lo) -> LDS 48 KB.
// 512 threads = 8 waves (wr = row half, wc = col quarter), per-wave 64x32 tile.
template <bool FINAL>
__global__ __launch_bounds__(512, 2)
void gru_fused(const u16* __restrict__ pMsg, const u16* __restrict__ pX, size_t psA,
               const u16* __restrict__ pWih, const u16* __restrict__ pWhh, size_t psB,
               const float* __restrict__ bih, const float* __restrict__ bhh,
               float* __restrict__ outF, u16* __restrict__ outP, size_t psO, int M) {
    // LDS (u16): A hi [128][32] at 0, lo at 4096 (16 KB);
    // B planes [128][32]: r-hi 8192, z-hi 12288, n-hi 16384, n-lo 20480 (32 KB).
    __shared__ u16 lds[24576];   // 48 KB

    const int tid = threadIdx.x;
    const int lane = tid & 63;
    const int wv = tid >> 6;           // 0..7
    const int wr = wv >> 2;            // 0..1 (64-row half)
    const int wc = wv & 3;             // 0..3 (32-col quarter)
    const int frow = lane & 15;
    const int kg = lane >> 4;
    const int rowBase = blockIdx.x * 128;
    const int colBase = blockIdx.y * 128;

    // staging: 48 x 1KB issues per k-iter, 6 per wave.
    // q = wv*6+j; q<16: A (plane q>>3, sub q&7); q>=16: qb=q-16 in [0,32):
    //   B plane qb>>3 (0:r-hi 1:z-hi 2:n-hi 3:n-lo), sub qb&7.
    int offj[6]; int ldsj[6]; bool isBj[6];
#pragma unroll
    for (int j = 0; j < 6; ++j) {
        int q = wv * 6 + j;
        bool isB = q >= 16;
        int eoff, ldso;
        if (!isB) {
            int p = (q >> 3) & 1; int sub = q & 7;
            int row = sub * 16 + (lane >> 2);
            int chunk = (lane & 3) ^ ((row >> 1) & 3);
            eoff = p * (int)psA + (rowBase + row) * DD + chunk * 8;
            ldso = q * 512;
        } else {
            int qb = q - 16;                 // 0..31
            int bp = qb >> 3;                // 0:r-hi 1:z-hi 2:n-hi 3:n-lo
            int sub = qb & 7;
            int row = sub * 16 + (lane >> 2);
            int chunk = (lane & 3) ^ ((row >> 1) & 3);
            int gate = (bp < 2) ? bp : 2;    // weight row block
            int p = (bp == 3) ? 1 : 0;       // lo plane only for n
            eoff = p * (int)psB + (gate * 256 + colBase + row) * DD + chunk * 8;
            ldso = 8192 + qb * 512;
        }
        offj[j] = eoff; ldsj[j] = ldso; isBj[j] = isB;
    }

    f32x4 accr[4][2] = {};
    f32x4 accz[4][2] = {};
    f32x4 accx[4][2] = {};
    f32x4 acch[4][2] = {};

#pragma unroll
    for (int half = 0; half < 2; ++half) {
        const u16* Ab = half ? pX : pMsg;
        const u16* Bb = half ? pWhh : pWih;
        for (int kc = 0; kc < DD; kc += BK) {
#pragma unroll
            for (int j = 0; j < 6; ++j)
                gload16((isBj[j] ? Bb : Ab) + offj[j] + kc, &lds[ldsj[j]]);
            __syncthreads();

            f16x8 af[2][4];
#pragma unroll
            for (int mf = 0; mf < 4; ++mf) {
                int row = wr * 64 + mf * 16 + frow;
                int off = row * 32 + ((kg ^ ((row >> 1) & 3)) * 8);
                af[0][mf] = *reinterpret_cast<const f16x8*>(&lds[off]);
                af[1][mf] = *reinterpret_cast<const f16x8*>(&lds[4096 + off]);
            }
#pragma unroll
            for (int nf = 0; nf < 2; ++nf) {
                int brow = wc * 32 + nf * 16 + frow;
                int bsw = brow * 32 + ((kg ^ ((brow >> 1) & 3)) * 8);
                f16x8 brh = *reinterpret_cast<const f16x8*>(&lds[8192 + bsw]);
                f16x8 bzh = *reinterpret_cast<const f16x8*>(&lds[12288 + bsw]);
                f16x8 bnh = *reinterpret_cast<const f16x8*>(&lds[16384 + bsw]);
                f16x8 bnl = *reinterpret_cast<const f16x8*>(&lds[20480 + bsw]);
#pragma unroll
                for (int mf = 0; mf < 4; ++mf) {
                    // r gate: hh + lh
                    f32x4 cr = accr[mf][nf];
                    cr = __builtin_amdgcn_mfma_f32_16x16x32_f16(af[0][mf], brh, cr, 0, 0, 0);
                    cr = __builtin_amdgcn_mfma_f32_16x16x32_f16(af[1][mf], brh, cr, 0, 0, 0);
                    accr[mf][nf] = cr;
                    // z gate: hh + lh
                    f32x4 cz = accz[mf][nf];
                    cz = __builtin_amdgcn_mfma_f32_16x16x32_f16(af[0][mf], bzh, cz, 0, 0, 0);
                    cz = __builtin_amdgcn_mfma_f32_16x16x32_f16(af[1][mf], bzh, cz, 0, 0, 0);
                    accz[mf][nf] = cz;
                    // n gate: hh + hl + lh
                    f32x4 cn = (half == 0) ? accx[mf][nf] : acch[mf][nf];
                    cn = __builtin_amdgcn_mfma_f32_16x16x32_f16(af[0][mf], bnh, cn, 0, 0, 0);
                    cn = __builtin_amdgcn_mfma_f32_16x16x32_f16(af[0][mf], bnl, cn, 0, 0, 0);
                    cn = __builtin_amdgcn_mfma_f32_16x16x32_f16(af[1][mf], bnh, cn, 0, 0, 0);
                    if (half == 0) accx[mf][nf] = cn; else acch[mf][nf] = cn;
                }
            }
            __syncthreads();
        }
    }

    // epilogue: full GRU update (R13-identical)
#pragma unroll
    for (int nf = 0; nf < 2; ++nf) {
        int gc = colBase + wc * 32 + nf * 16 + frow;
        float br = bih[gc] + bhh[gc];
        float bz = bih[256 + gc] + bhh[256 + gc];
        float bx = bih[512 + gc];
        float bh = bhh[512 + gc];
#pragma unroll
        for (int mf = 0; mf < 4; ++mf) {
#pragma unroll
            for (int j = 0; j < 4; ++j) {
                int gr = rowBase + wr * 64 + mf * 16 + kg * 4 + j;
                if (gr < M) {
                    size_t off = (size_t)gr * DD + gc;
                    float r = sigmoidf_(accr[mf][nf][j] + br);
                    float z = sigmoidf_(accz[mf][nf][j] + bz);
                    float T = tanhf(accx[mf][nf][j] + bx + r * (acch[mf][nf][j] + bh));
                    float x = h2f(pX[off]) + h2f(pX[psA + off]);
                    float o = (1.0f - z) * T + z * x;
                    if (FINAL) outF[off] = o;
                    else       store_planes(outP, psO, off, o);
                }
            }
        }
    }
}

// ---------------- segment sum (gather over fp16 h table) -> msg planes ----------------
__global__ __launch_bounds__(256)
void segsum_kernel(const u16* __restrict__ hp, const int* __restrict__ row_ptr,
                   const int* __restrict__ csr_src, u16* __restrict__ msgP,
                   size_t ps, int n) {
    int node = blockIdx.x * 4 + threadIdx.y;
    if (node >= n) return;
    int d4 = threadIdx.x * 4;
    int s = row_ptr[node];
    int e = row_ptr[node + 1];
    float4 acc = make_float4(0.f, 0.f, 0.f, 0.f);
    for (int j = s; j < e; ++j) {
        int sn = csr_src[j];
        f16x4 v = *reinterpret_cast<const f16x4*>(&hp[(size_t)sn * DD + d4]);
        acc.x += (float)v[0]; acc.y += (float)v[1];
        acc.z += (float)v[2]; acc.w += (float)v[3];
    }
    size_t off = (size_t)node * DD + d4;
    u16 h0,l0,h1,l1,h2,l2,h3,l3;
    split2(acc.x, h0,l0); split2(acc.y, h1,l1);
    split2(acc.z, h2,l2); split2(acc.w, h3,l3);
    *reinterpret_cast<uint2*>(&msgP[off])      = make_uint2(pk(h0,h1), pk(h2,h3));
    *reinterpret_cast<uint2*>(&msgP[ps + off]) = make_uint2(pk(l0,l1), pk(l2,l3));
}

// ---------------- launch ----------------

extern "C" void kernel_launch(void* const* d_in, const int* in_sizes, int n_in,
                              void* d_out, int out_size, void* d_ws, size_t ws_size,
                              hipStream_t stream) {
    const float* x0  = (const float*)d_in[0];
    const float* W1  = (const float*)d_in[1];
    const float* b1  = (const float*)d_in[2];
    const float* W2  = (const float*)d_in[3];
    const float* b2  = (const float*)d_in[4];
    const float* Wih = (const float*)d_in[5];
    const float* bih = (const float*)d_in[6];
    const float* Whh = (const float*)d_in[7];
    const float* bhh = (const float*)d_in[8];
    const int*   src = (const int*)d_in[9];
    const int*   dst = (const int*)d_in[10];

    // workspace layout (~211.3 MB — proven footprint)
    char* ws = (char*)d_ws;
    const size_t PSA = (size_t)NNP * DD;
    const size_t SP  = PSA * 2 * sizeof(u16);
    const size_t NB  = PSA * sizeof(float);
    const size_t PSW2 = (size_t)DD * DD;
    const size_t PSW3 = (size_t)3 * DD * DD;
    u16* XP0   = (u16*)(ws);
    u16* XP1   = (u16*)(ws + SP);
    u16* TP    = (u16*)(ws + 2 * SP);
    u16* HP    = (u16*)(ws + 3 * SP);
    u16* W1P   = (u16*)(ws + 3 * SP + NB);
    u16* W2P   = W1P + 2 * PSW2;
    u16* WIHP  = W2P + 2 * PSW2;
    u16* WHHP  = WIHP + 2 * PSW3;
    int* counts  = (int*)(WHHP + 2 * PSW3);
    int* cursor  = counts + NN;
    int* row_ptr = cursor + NN;
    int* csr     = row_ptr + NN + 8;
    const size_t needed = 3 * SP + NB + (4 * PSW2 + 4 * PSW3) * sizeof(u16)
                        + (size_t)(2 * NN + NN + 9 + NE) * sizeof(int);
    if (ws_size < needed) return;

    float* FOUT = (float*)d_out;

    // CSR build
    zero_kernel<<<(2 * NN + 255) / 256, 256, 0, stream>>>(counts, 2 * NN);
    hist_kernel<<<(NE + 255) / 256, 256, 0, stream>>>(dst, counts, NE);
    scan_kernel<<<1, 1024, 0, stream>>>(counts, row_ptr, NN);
    fill_kernel<<<(NE + 255) / 256, 256, 0, stream>>>(src, dst, row_ptr, cursor, csr, NE);

    // pre-split weights (once) and x0 -> XP0
    split_rows<<<DD, 256, 0, stream>>>(W1, W1P, PSW2, DD);
    split_rows<<<DD, 256, 0, stream>>>(W2, W2P, PSW2, DD);
    split_rows<<<3 * DD, 256, 0, stream>>>(Wih, WIHP, PSW3, 3 * DD);
    split_rows<<<3 * DD, 256, 0, stream>>>(Whh, WHHP, PSW3, 3 * DD);
    split_rows<<<NNP, 256, 0, stream>>>(x0, XP0, PSA, NN);

    const dim3 gridGRU(NNP / 128, 2);   // 391 x 2, 512-thread blocks

    for (int s = 0; s < NSTEPS; ++s) {
        u16* XPc = (s & 1) ? XP1 : XP0;
        u16* XPn = (s & 1) ? XP0 : XP1;

        // h = MLP(x) -> HP (single fp16 plane), t1 never touches HBM
        mlp_fused<<<NNP / 32, 256, 0, stream>>>(
            XPc, PSA, W1P, W2P, PSW2, b1, b2, HP, NN);
        // msg = segment_sum(h[src], dst) -> TP planes
        segsum_kernel<<<dim3((NN + 3) / 4), dim3(64, 4), 0, stream>>>(
            HP, row_ptr, csr, TP, PSA, NN);
        // full GRU update -> x_next planes (final: fp32 d_out)
        if (s < NSTEPS - 1) {
            gru_fused<false><<<gridGRU, 512, 0, stream>>>(
                TP, XPc, PSA, WIHP, WHHP, PSW3, bih, bhh,
                nullptr, XPn, PSA, NN);
        } else {
            gru_fused<true><<<gridGRU, 512, 0, stream>>>(
                TP, XPc, PSA, WIHP, WHHP, PSW3, bih, bhh,
                FOUT, nullptr, 0, NN);
        }
    }
}

// Round 16
// 2010.508 us; speedup vs baseline: 2.2815x; 1.0943x over previous
//
#include <hip/hip_runtime.h>
#include <hip/hip_bf16.h>
#include <math.h>

// Problem constants
#define NN 50000
#define NNP 50048       // rows padded to multiple of 128
#define NE 800000
#define DD 256
#define NSTEPS 6

#define BK 32

typedef unsigned short u16;
typedef _Float16 f16x8 __attribute__((ext_vector_type(8)));
typedef _Float16 f16x4 __attribute__((ext_vector_type(4)));
typedef float f32x4 __attribute__((ext_vector_type(4)));

__device__ __forceinline__ float sigmoidf_(float v) {
    return 1.0f / (1.0f + expf(-v));
}
__device__ __forceinline__ u16 f2h(float v) {
    _Float16 h = (_Float16)v;            // RNE
    u16 u; __builtin_memcpy(&u, &h, 2); return u;
}
__device__ __forceinline__ float h2f(u16 u) {
    _Float16 h; __builtin_memcpy(&h, &u, 2); return (float)h;
}
// fp16 2-way split: v ~= h + l to 2^-22 relative
__device__ __forceinline__ void split2(float v, u16& h, u16& l) {
    h = f2h(v);
    float r = v - h2f(h);
    l = f2h(r);
}
__device__ __forceinline__ unsigned pk(u16 a, u16 b) {
    return (unsigned)a | ((unsigned)b << 16);
}
__device__ __forceinline__ void store_planes(u16* base, size_t ps, size_t off, float v) {
    u16 h, l; split2(v, h, l);
    base[off] = h; base[ps + off] = l;
}
__device__ __forceinline__ void gload16(const void* g, void* l) {
    __builtin_amdgcn_global_load_lds(
        (const __attribute__((address_space(1))) void*)g,
        (__attribute__((address_space(3))) void*)l, 16, 0, 0);
}

// ---------------- CSR build (verified R1-R15) ----------------

__global__ void zero_kernel(int* __restrict__ p, int n) {
    int i = blockIdx.x * blockDim.x + threadIdx.x;
    if (i < n) p[i] = 0;
}
__global__ void hist_kernel(const int* __restrict__ dst, int* __restrict__ counts, int E) {
    int e = blockIdx.x * blockDim.x + threadIdx.x;
    if (e < E) atomicAdd(&counts[dst[e]], 1);
}
__global__ void scan_kernel(const int* __restrict__ counts, int* __restrict__ row_ptr, int n) {
    __shared__ int buf[1024];
    __shared__ int carry;
    const int tid = threadIdx.x;
    if (tid == 0) carry = 0;
    __syncthreads();
    for (int base = 0; base < n; base += 1024) {
        int i = base + tid;
        int v = (i < n) ? counts[i] : 0;
        buf[tid] = v;
        __syncthreads();
        for (int off = 1; off < 1024; off <<= 1) {
            int t = (tid >= off) ? buf[tid - off] : 0;
            __syncthreads();
            buf[tid] += t;
            __syncthreads();
        }
        if (i < n) row_ptr[i] = carry + buf[tid] - v;
        __syncthreads();
        if (tid == 0) carry += buf[1023];
        __syncthreads();
    }
    if (threadIdx.x == 0) row_ptr[n] = carry;
}
__global__ void fill_kernel(const int* __restrict__ src, const int* __restrict__ dst,
                            const int* __restrict__ row_ptr, int* __restrict__ cursor,
                            int* __restrict__ csr_src, int E) {
    int e = blockIdx.x * blockDim.x + threadIdx.x;
    if (e < E) {
        int d = dst[e];
        int p = atomicAdd(&cursor[d], 1);
        csr_src[row_ptr[d] + p] = src[e];
    }
}

// ---------------- fp32 -> 2 fp16 planes (rows padded w/ zero) ----------------
__global__ void split_rows(const float* __restrict__ src, u16* __restrict__ dst,
                           size_t pstride, int srcRows) {
    int row = blockIdx.x;
    int col = threadIdx.x;
    size_t off = (size_t)row * DD + col;
    float v = (row < srcRows) ? src[off] : 0.0f;
    store_planes(dst, pstride, off, v);
}

// ---------------- fused MLP: h = (ReLU(xh@W1^T+b1))@W2^T + b2 -> fp16 ----------------
// Phase 1 A-operand: x hi-plane only (2-term xh*(W1h+W1l); err ~2^-11, t1 is fp16 anyway).
__global__ __launch_bounds__(256, 3)
void mlp_fused(const u16* __restrict__ pX,
               const u16* __restrict__ W1P, const u16* __restrict__ W2P, size_t psW,
               const float* __restrict__ b1, const float* __restrict__ b2,
               u16* __restrict__ HP, int M) {
    // LDS (u16): A_h 2 subtiles @0 (1024); W 2 planes x 16 subtiles @1024 (16384);
    // t1 [32][256] swizzled @17408 (8192). Total 25600 u16 = 51.2 KB.
    __shared__ u16 lds[25600];
    const int T1B = 17408;

    const int tid = threadIdx.x;
    const int lane = tid & 63;
    const int wv = tid >> 6;           // col quarter 0..3
    const int frow = lane & 15;
    const int kg = lane >> 4;
    const int rowBase = blockIdx.x * 32;

    // staging: 34 x 1KB issues per k-iter (A 2 + W 32), up to 9 per wave.
    int offj[9]; int ldsj[9]; bool isWj[9]; bool actj[9];
#pragma unroll
    for (int j = 0; j < 9; ++j) {
        int q = wv * 9 + j;
        actj[j] = q < 34;
        int row, ldso, eoff = 0;
        bool isW = q >= 2;
        if (q < 2) {
            row = q * 16 + (lane >> 2);
            int chunk = (lane & 3) ^ ((row >> 1) & 3);
            eoff = (rowBase + row) * DD + chunk * 8;
            ldso = q * 512;
        } else {
            int qw = (q - 2) & 31;
            int plane = qw >> 4; int sub = qw & 15;
            row = sub * 16 + (lane >> 2);
            int chunk = (lane & 3) ^ ((row >> 1) & 3);
            eoff = plane * (int)psW + row * DD + chunk * 8;
            ldso = 1024 + qw * 512;
        }
        offj[j] = eoff; ldsj[j] = ldso; isWj[j] = isW;
    }

    // phase 1: t1 = ReLU(xh @ W1^T + b1)
    f32x4 acc1[2][4] = {};
    for (int kc = 0; kc < DD; kc += BK) {
#pragma unroll
        for (int j = 0; j < 9; ++j)
            if (actj[j]) gload16((isWj[j] ? W1P : pX) + offj[j] + kc, &lds[ldsj[j]]);
        __syncthreads();

        f16x8 af[2];
#pragma unroll
        for (int mf = 0; mf < 2; ++mf) {
            int row = mf * 16 + frow;
            int off = row * 32 + ((kg ^ ((row >> 1) & 3)) * 8);
            af[mf] = *reinterpret_cast<const f16x8*>(&lds[off]);
        }
#pragma unroll
        for (int nf = 0; nf < 4; ++nf) {
            int brow = wv * 64 + nf * 16 + frow;
            int boff = 1024 + brow * 32 + ((kg ^ ((brow >> 1) & 3)) * 8);
            f16x8 bh = *reinterpret_cast<const f16x8*>(&lds[boff]);
            f16x8 bl = *reinterpret_cast<const f16x8*>(&lds[boff + 8192]);
#pragma unroll
            for (int mf = 0; mf < 2; ++mf) {
                f32x4 c = acc1[mf][nf];
                c = __builtin_amdgcn_mfma_f32_16x16x32_f16(af[mf], bh, c, 0, 0, 0);
                c = __builtin_amdgcn_mfma_f32_16x16x32_f16(af[mf], bl, c, 0, 0, 0);
                acc1[mf][nf] = c;
            }
        }
        __syncthreads();
    }

    // t1 -> LDS fp16 (swizzled: chunk index XOR (row&7))
#pragma unroll
    for (int nf = 0; nf < 4; ++nf) {
        int col = wv * 64 + nf * 16 + frow;
        float bb = b1[col];
        int c8 = col >> 3, ci = col & 7;
#pragma unroll
        for (int mf = 0; mf < 2; ++mf) {
#pragma unroll
            for (int j = 0; j < 4; ++j) {
                int row = mf * 16 + kg * 4 + j;
                float v = fmaxf(acc1[mf][nf][j] + bb, 0.0f);
                lds[T1B + row * 256 + ((c8 ^ (row & 7)) * 8) + ci] = f2h(v);
            }
        }
    }
    __syncthreads();

    // phase 2: h = t1 @ W2^T + b2 (2-term)
    f32x4 acc2[2][4] = {};
    for (int kc = 0; kc < DD; kc += BK) {
#pragma unroll
        for (int j = 0; j < 9; ++j)
            if (actj[j] && isWj[j]) gload16(W2P + offj[j] + kc, &lds[ldsj[j]]);
        __syncthreads();

        f16x8 at[2];
#pragma unroll
        for (int mf = 0; mf < 2; ++mf) {
            int row = mf * 16 + frow;
            int qc = (kc >> 3) + kg;
            at[mf] = *reinterpret_cast<const f16x8*>(
                &lds[T1B + row * 256 + ((qc ^ (row & 7)) * 8)]);
        }
#pragma unroll
        for (int nf = 0; nf < 4; ++nf) {
            int brow = wv * 64 + nf * 16 + frow;
            int boff = 1024 + brow * 32 + ((kg ^ ((brow >> 1) & 3)) * 8);
            f16x8 bh = *reinterpret_cast<const f16x8*>(&lds[boff]);
            f16x8 bl = *reinterpret_cast<const f16x8*>(&lds[boff + 8192]);
#pragma unroll
            for (int mf = 0; mf < 2; ++mf) {
                f32x4 c = acc2[mf][nf];
                c = __builtin_amdgcn_mfma_f32_16x16x32_f16(at[mf], bh, c, 0, 0, 0);
                c = __builtin_amdgcn_mfma_f32_16x16x32_f16(at[mf], bl, c, 0, 0, 0);
                acc2[mf][nf] = c;
            }
        }
        __syncthreads();
    }

#pragma unroll
    for (int nf = 0; nf < 4; ++nf) {
        int col = wv * 64 + nf * 16 + frow;
        float bb = b2[col];
#pragma unroll
        for (int mf = 0; mf < 2; ++mf) {
#pragma unroll
            for (int j = 0; j < 4; ++j) {
                int gr = rowBase + mf * 16 + kg * 4 + j;
                if (gr < M) HP[(size_t)gr * DD + col] = f2h(acc2[mf][nf][j] + bb);
            }
        }
    }
}

// ---------------- fused GRU: single-plane A in gates ----------------
// A = msg_h (half 0) / x_h (half 1), ONE fp16 plane. Gates: r = ah*Brh (1 MFMA),
// z = ah*Bzh (1), n = ah*(Bnh+Bnl) (2) -> 32 MFMA/wave/k-iter (was 56).
// Gate injections ~2^-10, smoothed by sigma/tanh (R14/R15 validated class).
// x state stays 2-plane; blend in epilogue keeps 2^-22 carry precision.
// LDS 40 KB; 512 threads = 8 waves (wr row-half, wc col-quarter), 64x32/wave.
template <bool FINAL>
__global__ __launch_bounds__(512, 2)
void gru_fused(const u16* __restrict__ pMsgH, const u16* __restrict__ pX, size_t psA,
               const u16* __restrict__ pWih, const u16* __restrict__ pWhh, size_t psB,
               const float* __restrict__ bih, const float* __restrict__ bhh,
               float* __restrict__ outF, u16* __restrict__ outP, size_t psO, int M) {
    // LDS (u16): A_h [128][32] @0 (4096); B panels [128][32] @4096+bp*4096:
    // r-hi 4096, z-hi 8192, n-hi 12288, n-lo 16384. Total 20480 u16 = 40 KB.
    __shared__ u16 lds[20480];

    const int tid = threadIdx.x;
    const int lane = tid & 63;
    const int wv = tid >> 6;           // 0..7
    const int wr = wv >> 2;            // 0..1 (64-row half)
    const int wc = wv & 3;             // 0..3 (32-col quarter)
    const int frow = lane & 15;
    const int kg = lane >> 4;
    const int rowBase = blockIdx.x * 128;
    const int colBase = blockIdx.y * 128;

    // staging: 40 x 1KB issues per k-iter, 5 per wave.
    // q = wv*5+j; q<8: A sub q; q>=8: qb=q-8: B plane qb>>3 (0:r-hi 1:z-hi
    // 2:n-hi 3:n-lo), sub qb&7.
    int offj[5]; int ldsj[5]; bool isBj[5];
#pragma unroll
    for (int j = 0; j < 5; ++j) {
        int q = wv * 5 + j;
        bool isB = q >= 8;
        int eoff, ldso;
        if (!isB) {
            int row = q * 16 + (lane >> 2);
            int chunk = (lane & 3) ^ ((row >> 1) & 3);
            eoff = (rowBase + row) * DD + chunk * 8;
            ldso = q * 512;
        } else {
            int qb = q - 8;                  // 0..31
            int bp = qb >> 3;                // 0:r-hi 1:z-hi 2:n-hi 3:n-lo
            int sub = qb & 7;
            int row = sub * 16 + (lane >> 2);
            int chunk = (lane & 3) ^ ((row >> 1) & 3);
            int gate = (bp < 2) ? bp : 2;
            int p = (bp == 3) ? 1 : 0;
            eoff = p * (int)psB + (gate * 256 + colBase + row) * DD + chunk * 8;
            ldso = 4096 + qb * 512;
        }
        offj[j] = eoff; ldsj[j] = ldso; isBj[j] = isB;
    }

    f32x4 accr[4][2] = {};
    f32x4 accz[4][2] = {};
    f32x4 accx[4][2] = {};
    f32x4 acch[4][2] = {};

#pragma unroll
    for (int half = 0; half < 2; ++half) {
        const u16* Ab = half ? pX : pMsgH;   // hi plane only
        const u16* Bb = half ? pWhh : pWih;
        for (int kc = 0; kc < DD; kc += BK) {
#pragma unroll
            for (int j = 0; j < 5; ++j)
                gload16((isBj[j] ? Bb : Ab) + offj[j] + kc, &lds[ldsj[j]]);
            __syncthreads();

            f16x8 af[4];
#pragma unroll
            for (int mf = 0; mf < 4; ++mf) {
                int row = wr * 64 + mf * 16 + frow;
                af[mf] = *reinterpret_cast<const f16x8*>(
                    &lds[row * 32 + ((kg ^ ((row >> 1) & 3)) * 8)]);
            }
#pragma unroll
            for (int nf = 0; nf < 2; ++nf) {
                int brow = wc * 32 + nf * 16 + frow;
                int bsw = brow * 32 + ((kg ^ ((brow >> 1) & 3)) * 8);
                f16x8 brh = *reinterpret_cast<const f16x8*>(&lds[4096 + bsw]);
                f16x8 bzh = *reinterpret_cast<const f16x8*>(&lds[8192 + bsw]);
                f16x8 bnh = *reinterpret_cast<const f16x8*>(&lds[12288 + bsw]);
                f16x8 bnl = *reinterpret_cast<const f16x8*>(&lds[16384 + bsw]);
#pragma unroll
                for (int mf = 0; mf < 4; ++mf) {
                    accr[mf][nf] = __builtin_amdgcn_mfma_f32_16x16x32_f16(
                        af[mf], brh, accr[mf][nf], 0, 0, 0);
                    accz[mf][nf] = __builtin_amdgcn_mfma_f32_16x16x32_f16(
                        af[mf], bzh, accz[mf][nf], 0, 0, 0);
                    f32x4 cn = (half == 0) ? accx[mf][nf] : acch[mf][nf];
                    cn = __builtin_amdgcn_mfma_f32_16x16x32_f16(af[mf], bnh, cn, 0, 0, 0);
                    cn = __builtin_amdgcn_mfma_f32_16x16x32_f16(af[mf], bnl, cn, 0, 0, 0);
                    if (half == 0) accx[mf][nf] = cn; else acch[mf][nf] = cn;
                }
            }
            __syncthreads();
        }
    }

    // epilogue: full GRU update (x blend uses both planes — full precision carry)
#pragma unroll
    for (int nf = 0; nf < 2; ++nf) {
        int gc = colBase + wc * 32 + nf * 16 + frow;
        float br = bih[gc] + bhh[gc];
        float bz = bih[256 + gc] + bhh[256 + gc];
        float bx = bih[512 + gc];
        float bh = bhh[512 + gc];
#pragma unroll
        for (int mf = 0; mf < 4; ++mf) {
#pragma unroll
            for (int j = 0; j < 4; ++j) {
                int gr = rowBase + wr * 64 + mf * 16 + kg * 4 + j;
                if (gr < M) {
                    size_t off = (size_t)gr * DD + gc;
                    float r = sigmoidf_(accr[mf][nf][j] + br);
                    float z = sigmoidf_(accz[mf][nf][j] + bz);
                    float T = tanhf(accx[mf][nf][j] + bx + r * (acch[mf][nf][j] + bh));
                    float x = h2f(pX[off]) + h2f(pX[psA + off]);
                    float o = (1.0f - z) * T + z * x;
                    if (FINAL) outF[off] = o;
                    else       store_planes(outP, psO, off, o);
                }
            }
        }
    }
}

// ---------------- segment sum -> msg single fp16 plane ----------------
__global__ __launch_bounds__(256)
void segsum_kernel(const u16* __restrict__ hp, const int* __restrict__ row_ptr,
                   const int* __restrict__ csr_src, u16* __restrict__ msgH, int n) {
    int node = blockIdx.x * 4 + threadIdx.y;
    if (node >= n) return;
    int d4 = threadIdx.x * 4;
    int s = row_ptr[node];
    int e = row_ptr[node + 1];
    float4 acc = make_float4(0.f, 0.f, 0.f, 0.f);
    for (int j = s; j < e; ++j) {
        int sn = csr_src[j];
        f16x4 v = *reinterpret_cast<const f16x4*>(&hp[(size_t)sn * DD + d4]);
        acc.x += (float)v[0]; acc.y += (float)v[1];
        acc.z += (float)v[2]; acc.w += (float)v[3];
    }
    size_t off = (size_t)node * DD + d4;
    *reinterpret_cast<uint2*>(&msgH[off]) =
        make_uint2(pk(f2h(acc.x), f2h(acc.y)), pk(f2h(acc.z), f2h(acc.w)));
}

// ---------------- launch ----------------

extern "C" void kernel_launch(void* const* d_in, const int* in_sizes, int n_in,
                              void* d_out, int out_size, void* d_ws, size_t ws_size,
                              hipStream_t stream) {
    const float* x0  = (const float*)d_in[0];
    const float* W1  = (const float*)d_in[1];
    const float* b1  = (const float*)d_in[2];
    const float* W2  = (const float*)d_in[3];
    const float* b2  = (const float*)d_in[4];
    const float* Wih = (const float*)d_in[5];
    const float* bih = (const float*)d_in[6];
    const float* Whh = (const float*)d_in[7];
    const float* bhh = (const float*)d_in[8];
    const int*   src = (const int*)d_in[9];
    const int*   dst = (const int*)d_in[10];

    // workspace layout (~211.3 MB — proven footprint)
    char* ws = (char*)d_ws;
    const size_t PSA = (size_t)NNP * DD;
    const size_t SP  = PSA * 2 * sizeof(u16);
    const size_t NB  = PSA * sizeof(float);
    const size_t PSW2 = (size_t)DD * DD;
    const size_t PSW3 = (size_t)3 * DD * DD;
    u16* XP0   = (u16*)(ws);
    u16* XP1   = (u16*)(ws + SP);
    u16* TP    = (u16*)(ws + 2 * SP);       // msg single fp16 plane
    u16* HP    = (u16*)(ws + 3 * SP);       // h single fp16 plane
    u16* W1P   = (u16*)(ws + 3 * SP + NB);
    u16* W2P   = W1P + 2 * PSW2;
    u16* WIHP  = W2P + 2 * PSW2;
    u16* WHHP  = WIHP + 2 * PSW3;
    int* counts  = (int*)(WHHP + 2 * PSW3);
    int* cursor  = counts + NN;
    int* row_ptr = cursor + NN;
    int* csr     = row_ptr + NN + 8;
    const size_t needed = 3 * SP + NB + (4 * PSW2 + 4 * PSW3) * sizeof(u16)
                        + (size_t)(2 * NN + NN + 9 + NE) * sizeof(int);
    if (ws_size < needed) return;

    float* FOUT = (float*)d_out;

    // CSR build
    zero_kernel<<<(2 * NN + 255) / 256, 256, 0, stream>>>(counts, 2 * NN);
    hist_kernel<<<(NE + 255) / 256, 256, 0, stream>>>(dst, counts, NE);
    scan_kernel<<<1, 1024, 0, stream>>>(counts, row_ptr, NN);
    fill_kernel<<<(NE + 255) / 256, 256, 0, stream>>>(src, dst, row_ptr, cursor, csr, NE);

    // pre-split weights (once) and x0 -> XP0
    split_rows<<<DD, 256, 0, stream>>>(W1, W1P, PSW2, DD);
    split_rows<<<DD, 256, 0, stream>>>(W2, W2P, PSW2, DD);
    split_rows<<<3 * DD, 256, 0, stream>>>(Wih, WIHP, PSW3, 3 * DD);
    split_rows<<<3 * DD, 256, 0, stream>>>(Whh, WHHP, PSW3, 3 * DD);
    split_rows<<<NNP, 256, 0, stream>>>(x0, XP0, PSA, NN);

    const dim3 gridGRU(NNP / 128, 2);   // 391 x 2, 512-thread blocks

    for (int s = 0; s < NSTEPS; ++s) {
        u16* XPc = (s & 1) ? XP1 : XP0;
        u16* XPn = (s & 1) ? XP0 : XP1;

        // h = MLP(x) -> HP (single fp16 plane)
        mlp_fused<<<NNP / 32, 256, 0, stream>>>(
            XPc, W1P, W2P, PSW2, b1, b2, HP, NN);
        // msg = segment_sum(h[src], dst) -> TP (single fp16 plane)
        segsum_kernel<<<dim3((NN + 3) / 4), dim3(64, 4), 0, stream>>>(
            HP, row_ptr, csr, TP, NN);
        // full GRU update -> x_next planes (final: fp32 d_out)
        if (s < NSTEPS - 1) {
            gru_fused<false><<<gridGRU, 512, 0, stream>>>(
                TP, XPc, PSA, WIHP, WHHP, PSW3, bih, bhh,
                nullptr, XPn, PSA, NN);
        } else {
            gru_fused<true><<<gridGRU, 512, 0, stream>>>(
                TP, XPc, PSA, WIHP, WHHP, PSW3, bih, bhh,
                FOUT, nullptr, 0, NN);
        }
    }
}

// Round 17
// 2001.456 us; speedup vs baseline: 2.2919x; 1.0045x over previous
//
#include <hip/hip_runtime.h>
#include <hip/hip_bf16.h>
#include <math.h>

// Problem constants
#define NN 50000
#define NNP 50048       // rows padded to multiple of 128
#define NE 800000
#define DD 256
#define NSTEPS 6

#define BK 32

typedef unsigned short u16;
typedef _Float16 f16x8 __attribute__((ext_vector_type(8)));
typedef _Float16 f16x4 __attribute__((ext_vector_type(4)));
typedef float f32x4 __attribute__((ext_vector_type(4)));

__device__ __forceinline__ float sigmoidf_(float v) {
    return 1.0f / (1.0f + expf(-v));
}
__device__ __forceinline__ u16 f2h(float v) {
    _Float16 h = (_Float16)v;            // RNE
    u16 u; __builtin_memcpy(&u, &h, 2); return u;
}
__device__ __forceinline__ float h2f(u16 u) {
    _Float16 h; __builtin_memcpy(&h, &u, 2); return (float)h;
}
// fp16 2-way split: v ~= h + l to 2^-22 relative
__device__ __forceinline__ void split2(float v, u16& h, u16& l) {
    h = f2h(v);
    float r = v - h2f(h);
    l = f2h(r);
}
__device__ __forceinline__ unsigned pk(u16 a, u16 b) {
    return (unsigned)a | ((unsigned)b << 16);
}
__device__ __forceinline__ void store_planes(u16* base, size_t ps, size_t off, float v) {
    u16 h, l; split2(v, h, l);
    base[off] = h; base[ps + off] = l;
}
__device__ __forceinline__ void gload16(const void* g, void* l) {
    __builtin_amdgcn_global_load_lds(
        (const __attribute__((address_space(1))) void*)g,
        (__attribute__((address_space(3))) void*)l, 16, 0, 0);
}

// ---------------- CSR build (verified R1-R16) ----------------

__global__ void zero_kernel(int* __restrict__ p, int n) {
    int i = blockIdx.x * blockDim.x + threadIdx.x;
    if (i < n) p[i] = 0;
}
__global__ void hist_kernel(const int* __restrict__ dst, int* __restrict__ counts, int E) {
    int e = blockIdx.x * blockDim.x + threadIdx.x;
    if (e < E) atomicAdd(&counts[dst[e]], 1);
}
__global__ void scan_kernel(const int* __restrict__ counts, int* __restrict__ row_ptr, int n) {
    __shared__ int buf[1024];
    __shared__ int carry;
    const int tid = threadIdx.x;
    if (tid == 0) carry = 0;
    __syncthreads();
    for (int base = 0; base < n; base += 1024) {
        int i = base + tid;
        int v = (i < n) ? counts[i] : 0;
        buf[tid] = v;
        __syncthreads();
        for (int off = 1; off < 1024; off <<= 1) {
            int t = (tid >= off) ? buf[tid - off] : 0;
            __syncthreads();
            buf[tid] += t;
            __syncthreads();
        }
        if (i < n) row_ptr[i] = carry + buf[tid] - v;
        __syncthreads();
        if (tid == 0) carry += buf[1023];
        __syncthreads();
    }
    if (threadIdx.x == 0) row_ptr[n] = carry;
}
__global__ void fill_kernel(const int* __restrict__ src, const int* __restrict__ dst,
                            const int* __restrict__ row_ptr, int* __restrict__ cursor,
                            int* __restrict__ csr_src, int E) {
    int e = blockIdx.x * blockDim.x + threadIdx.x;
    if (e < E) {
        int d = dst[e];
        int p = atomicAdd(&cursor[d], 1);
        csr_src[row_ptr[d] + p] = src[e];
    }
}

// ---------------- fp32 -> 2 fp16 planes (rows padded w/ zero) ----------------
__global__ void split_rows(const float* __restrict__ src, u16* __restrict__ dst,
                           size_t pstride, int srcRows) {
    int row = blockIdx.x;
    int col = threadIdx.x;
    size_t off = (size_t)row * DD + col;
    float v = (row < srcRows) ? src[off] : 0.0f;
    store_planes(dst, pstride, off, v);
}

// ---------------- fused MLP (R16-verified) ----------------
__global__ __launch_bounds__(256, 3)
void mlp_fused(const u16* __restrict__ pX,
               const u16* __restrict__ W1P, const u16* __restrict__ W2P, size_t psW,
               const float* __restrict__ b1, const float* __restrict__ b2,
               u16* __restrict__ HP, int M) {
    // LDS (u16): A_h 2 subtiles @0 (1024); W 2 planes x 16 subtiles @1024 (16384);
    // t1 [32][256] swizzled @17408 (8192). Total 25600 u16 = 51.2 KB.
    __shared__ u16 lds[25600];
    const int T1B = 17408;

    const int tid = threadIdx.x;
    const int lane = tid & 63;
    const int wv = tid >> 6;           // col quarter 0..3
    const int frow = lane & 15;
    const int kg = lane >> 4;
    const int rowBase = blockIdx.x * 32;

    int offj[9]; int ldsj[9]; bool isWj[9]; bool actj[9];
#pragma unroll
    for (int j = 0; j < 9; ++j) {
        int q = wv * 9 + j;
        actj[j] = q < 34;
        int row, ldso, eoff = 0;
        bool isW = q >= 2;
        if (q < 2) {
            row = q * 16 + (lane >> 2);
            int chunk = (lane & 3) ^ ((row >> 1) & 3);
            eoff = (rowBase + row) * DD + chunk * 8;
            ldso = q * 512;
        } else {
            int qw = (q - 2) & 31;
            int plane = qw >> 4; int sub = qw & 15;
            row = sub * 16 + (lane >> 2);
            int chunk = (lane & 3) ^ ((row >> 1) & 3);
            eoff = plane * (int)psW + row * DD + chunk * 8;
            ldso = 1024 + qw * 512;
        }
        offj[j] = eoff; ldsj[j] = ldso; isWj[j] = isW;
    }

    // phase 1: t1 = ReLU(xh @ W1^T + b1)
    f32x4 acc1[2][4] = {};
    for (int kc = 0; kc < DD; kc += BK) {
#pragma unroll
        for (int j = 0; j < 9; ++j)
            if (actj[j]) gload16((isWj[j] ? W1P : pX) + offj[j] + kc, &lds[ldsj[j]]);
        __syncthreads();

        f16x8 af[2];
#pragma unroll
        for (int mf = 0; mf < 2; ++mf) {
            int row = mf * 16 + frow;
            int off = row * 32 + ((kg ^ ((row >> 1) & 3)) * 8);
            af[mf] = *reinterpret_cast<const f16x8*>(&lds[off]);
        }
#pragma unroll
        for (int nf = 0; nf < 4; ++nf) {
            int brow = wv * 64 + nf * 16 + frow;
            int boff = 1024 + brow * 32 + ((kg ^ ((brow >> 1) & 3)) * 8);
            f16x8 bh = *reinterpret_cast<const f16x8*>(&lds[boff]);
            f16x8 bl = *reinterpret_cast<const f16x8*>(&lds[boff + 8192]);
#pragma unroll
            for (int mf = 0; mf < 2; ++mf) {
                f32x4 c = acc1[mf][nf];
                c = __builtin_amdgcn_mfma_f32_16x16x32_f16(af[mf], bh, c, 0, 0, 0);
                c = __builtin_amdgcn_mfma_f32_16x16x32_f16(af[mf], bl, c, 0, 0, 0);
                acc1[mf][nf] = c;
            }
        }
        __syncthreads();
    }

    // t1 -> LDS fp16 (swizzled: chunk index XOR (row&7))
#pragma unroll
    for (int nf = 0; nf < 4; ++nf) {
        int col = wv * 64 + nf * 16 + frow;
        float bb = b1[col];
        int c8 = col >> 3, ci = col & 7;
#pragma unroll
        for (int mf = 0; mf < 2; ++mf) {
#pragma unroll
            for (int j = 0; j < 4; ++j) {
                int row = mf * 16 + kg * 4 + j;
                float v = fmaxf(acc1[mf][nf][j] + bb, 0.0f);
                lds[T1B + row * 256 + ((c8 ^ (row & 7)) * 8) + ci] = f2h(v);
            }
        }
    }
    __syncthreads();

    // phase 2: h = t1 @ W2^T + b2 (2-term)
    f32x4 acc2[2][4] = {};
    for (int kc = 0; kc < DD; kc += BK) {
#pragma unroll
        for (int j = 0; j < 9; ++j)
            if (actj[j] && isWj[j]) gload16(W2P + offj[j] + kc, &lds[ldsj[j]]);
        __syncthreads();

        f16x8 at[2];
#pragma unroll
        for (int mf = 0; mf < 2; ++mf) {
            int row = mf * 16 + frow;
            int qc = (kc >> 3) + kg;
            at[mf] = *reinterpret_cast<const f16x8*>(
                &lds[T1B + row * 256 + ((qc ^ (row & 7)) * 8)]);
        }
#pragma unroll
        for (int nf = 0; nf < 4; ++nf) {
            int brow = wv * 64 + nf * 16 + frow;
            int boff = 1024 + brow * 32 + ((kg ^ ((brow >> 1) & 3)) * 8);
            f16x8 bh = *reinterpret_cast<const f16x8*>(&lds[boff]);
            f16x8 bl = *reinterpret_cast<const f16x8*>(&lds[boff + 8192]);
#pragma unroll
            for (int mf = 0; mf < 2; ++mf) {
                f32x4 c = acc2[mf][nf];
                c = __builtin_amdgcn_mfma_f32_16x16x32_f16(at[mf], bh, c, 0, 0, 0);
                c = __builtin_amdgcn_mfma_f32_16x16x32_f16(at[mf], bl, c, 0, 0, 0);
                acc2[mf][nf] = c;
            }
        }
        __syncthreads();
    }

#pragma unroll
    for (int nf = 0; nf < 4; ++nf) {
        int col = wv * 64 + nf * 16 + frow;
        float bb = b2[col];
#pragma unroll
        for (int mf = 0; mf < 2; ++mf) {
#pragma unroll
            for (int j = 0; j < 4; ++j) {
                int gr = rowBase + mf * 16 + kg * 4 + j;
                if (gr < M) HP[(size_t)gr * DD + col] = f2h(acc2[mf][nf][j] + bb);
            }
        }
    }
}

// ---------------- fused GRU: single-plane A gates, 2-subtile k-iter ----------------
// Same math as R16 (absmax-validated); two k-subtiles staged per barrier pair
// -> 16 barriers/dispatch instead of 32. LDS 80 KB; occupancy unchanged
// (VGPR-capped at 2 blocks/CU; 2 x 80 KB = CU LDS limit exactly).
template <bool FINAL>
__global__ __launch_bounds__(512, 2)
void gru_fused(const u16* __restrict__ pMsgH, const u16* __restrict__ pX, size_t psA,
               const u16* __restrict__ pWih, const u16* __restrict__ pWhh, size_t psB,
               const float* __restrict__ bih, const float* __restrict__ bhh,
               float* __restrict__ outF, u16* __restrict__ outP, size_t psO, int M) {
    // Per k-subtile half (20480 u16): A_h [128][32] @0 (4096); B panels @4096+bp*4096:
    // r-hi, z-hi, n-hi, n-lo. Two halves -> 40960 u16 = 80 KB.
    __shared__ u16 lds[40960];

    const int tid = threadIdx.x;
    const int lane = tid & 63;
    const int wv = tid >> 6;           // 0..7
    const int wr = wv >> 2;            // 0..1 (64-row half)
    const int wc = wv & 3;             // 0..3 (32-col quarter)
    const int frow = lane & 15;
    const int kg = lane >> 4;
    const int rowBase = blockIdx.x * 128;
    const int colBase = blockIdx.y * 128;

    // per-subtile staging map (R16-verified): 40 x 1KB issues, 5 per wave.
    int offj[5]; int ldsj[5]; bool isBj[5];
#pragma unroll
    for (int j = 0; j < 5; ++j) {
        int q = wv * 5 + j;
        bool isB = q >= 8;
        int eoff, ldso;
        if (!isB) {
            int row = q * 16 + (lane >> 2);
            int chunk = (lane & 3) ^ ((row >> 1) & 3);
            eoff = (rowBase + row) * DD + chunk * 8;
            ldso = q * 512;
        } else {
            int qb = q - 8;                  // 0..31
            int bp = qb >> 3;                // 0:r-hi 1:z-hi 2:n-hi 3:n-lo
            int sub = qb & 7;
            int row = sub * 16 + (lane >> 2);
            int chunk = (lane & 3) ^ ((row >> 1) & 3);
            int gate = (bp < 2) ? bp : 2;
            int p = (bp == 3) ? 1 : 0;
            eoff = p * (int)psB + (gate * 256 + colBase + row) * DD + chunk * 8;
            ldso = 4096 + qb * 512;
        }
        offj[j] = eoff; ldsj[j] = ldso; isBj[j] = isB;
    }

    f32x4 accr[4][2] = {};
    f32x4 accz[4][2] = {};
    f32x4 accx[4][2] = {};
    f32x4 acch[4][2] = {};

#pragma unroll
    for (int half = 0; half < 2; ++half) {
        const u16* Ab = half ? pX : pMsgH;   // hi plane only
        const u16* Bb = half ? pWhh : pWih;
        for (int kc = 0; kc < DD; kc += 2 * BK) {
            // stage BOTH k-subtiles, one barrier pair
#pragma unroll
            for (int j = 0; j < 5; ++j)
                gload16((isBj[j] ? Bb : Ab) + offj[j] + kc, &lds[ldsj[j]]);
#pragma unroll
            for (int j = 0; j < 5; ++j)
                gload16((isBj[j] ? Bb : Ab) + offj[j] + kc + BK, &lds[20480 + ldsj[j]]);
            __syncthreads();

#pragma unroll
            for (int st = 0; st < 2; ++st) {
                const u16* L = &lds[st * 20480];
                f16x8 af[4];
#pragma unroll
                for (int mf = 0; mf < 4; ++mf) {
                    int row = wr * 64 + mf * 16 + frow;
                    af[mf] = *reinterpret_cast<const f16x8*>(
                        &L[row * 32 + ((kg ^ ((row >> 1) & 3)) * 8)]);
                }
#pragma unroll
                for (int nf = 0; nf < 2; ++nf) {
                    int brow = wc * 32 + nf * 16 + frow;
                    int bsw = brow * 32 + ((kg ^ ((brow >> 1) & 3)) * 8);
                    f16x8 brh = *reinterpret_cast<const f16x8*>(&L[4096 + bsw]);
                    f16x8 bzh = *reinterpret_cast<const f16x8*>(&L[8192 + bsw]);
                    f16x8 bnh = *reinterpret_cast<const f16x8*>(&L[12288 + bsw]);
                    f16x8 bnl = *reinterpret_cast<const f16x8*>(&L[16384 + bsw]);
#pragma unroll
                    for (int mf = 0; mf < 4; ++mf) {
                        accr[mf][nf] = __builtin_amdgcn_mfma_f32_16x16x32_f16(
                            af[mf], brh, accr[mf][nf], 0, 0, 0);
                        accz[mf][nf] = __builtin_amdgcn_mfma_f32_16x16x32_f16(
                            af[mf], bzh, accz[mf][nf], 0, 0, 0);
                        f32x4 cn = (half == 0) ? accx[mf][nf] : acch[mf][nf];
                        cn = __builtin_amdgcn_mfma_f32_16x16x32_f16(af[mf], bnh, cn, 0, 0, 0);
                        cn = __builtin_amdgcn_mfma_f32_16x16x32_f16(af[mf], bnl, cn, 0, 0, 0);
                        if (half == 0) accx[mf][nf] = cn; else acch[mf][nf] = cn;
                    }
                }
            }
            __syncthreads();
        }
    }

    // epilogue: full GRU update (x blend uses both planes — full precision carry)
#pragma unroll
    for (int nf = 0; nf < 2; ++nf) {
        int gc = colBase + wc * 32 + nf * 16 + frow;
        float br = bih[gc] + bhh[gc];
        float bz = bih[256 + gc] + bhh[256 + gc];
        float bx = bih[512 + gc];
        float bh = bhh[512 + gc];
#pragma unroll
        for (int mf = 0; mf < 4; ++mf) {
#pragma unroll
            for (int j = 0; j < 4; ++j) {
                int gr = rowBase + wr * 64 + mf * 16 + kg * 4 + j;
                if (gr < M) {
                    size_t off = (size_t)gr * DD + gc;
                    float r = sigmoidf_(accr[mf][nf][j] + br);
                    float z = sigmoidf_(accz[mf][nf][j] + bz);
                    float T = tanhf(accx[mf][nf][j] + bx + r * (acch[mf][nf][j] + bh));
                    float x = h2f(pX[off]) + h2f(pX[psA + off]);
                    float o = (1.0f - z) * T + z * x;
                    if (FINAL) outF[off] = o;
                    else       store_planes(outP, psO, off, o);
                }
            }
        }
    }
}

// ---------------- segment sum -> msg single fp16 plane ----------------
__global__ __launch_bounds__(256)
void segsum_kernel(const u16* __restrict__ hp, const int* __restrict__ row_ptr,
                   const int* __restrict__ csr_src, u16* __restrict__ msgH, int n) {
    int node = blockIdx.x * 4 + threadIdx.y;
    if (node >= n) return;
    int d4 = threadIdx.x * 4;
    int s = row_ptr[node];
    int e = row_ptr[node + 1];
    float4 acc = make_float4(0.f, 0.f, 0.f, 0.f);
    for (int j = s; j < e; ++j) {
        int sn = csr_src[j];
        f16x4 v = *reinterpret_cast<const f16x4*>(&hp[(size_t)sn * DD + d4]);
        acc.x += (float)v[0]; acc.y += (float)v[1];
        acc.z += (float)v[2]; acc.w += (float)v[3];
    }
    size_t off = (size_t)node * DD + d4;
    *reinterpret_cast<uint2*>(&msgH[off]) =
        make_uint2(pk(f2h(acc.x), f2h(acc.y)), pk(f2h(acc.z), f2h(acc.w)));
}

// ---------------- launch ----------------

extern "C" void kernel_launch(void* const* d_in, const int* in_sizes, int n_in,
                              void* d_out, int out_size, void* d_ws, size_t ws_size,
                              hipStream_t stream) {
    const float* x0  = (const float*)d_in[0];
    const float* W1  = (const float*)d_in[1];
    const float* b1  = (const float*)d_in[2];
    const float* W2  = (const float*)d_in[3];
    const float* b2  = (const float*)d_in[4];
    const float* Wih = (const float*)d_in[5];
    const float* bih = (const float*)d_in[6];
    const float* Whh = (const float*)d_in[7];
    const float* bhh = (const float*)d_in[8];
    const int*   src = (const int*)d_in[9];
    const int*   dst = (const int*)d_in[10];

    // workspace layout (~211.3 MB — proven footprint)
    char* ws = (char*)d_ws;
    const size_t PSA = (size_t)NNP * DD;
    const size_t SP  = PSA * 2 * sizeof(u16);
    const size_t NB  = PSA * sizeof(float);
    const size_t PSW2 = (size_t)DD * DD;
    const size_t PSW3 = (size_t)3 * DD * DD;
    u16* XP0   = (u16*)(ws);
    u16* XP1   = (u16*)(ws + SP);
    u16* TP    = (u16*)(ws + 2 * SP);       // msg single fp16 plane
    u16* HP    = (u16*)(ws + 3 * SP);       // h single fp16 plane
    u16* W1P   = (u16*)(ws + 3 * SP + NB);
    u16* W2P   = W1P + 2 * PSW2;
    u16* WIHP  = W2P + 2 * PSW2;
    u16* WHHP  = WIHP + 2 * PSW3;
    int* counts  = (int*)(WHHP + 2 * PSW3);
    int* cursor  = counts + NN;
    int* row_ptr = cursor + NN;
    int* csr     = row_ptr + NN + 8;
    const size_t needed = 3 * SP + NB + (4 * PSW2 + 4 * PSW3) * sizeof(u16)
                        + (size_t)(2 * NN + NN + 9 + NE) * sizeof(int);
    if (ws_size < needed) return;

    float* FOUT = (float*)d_out;

    // CSR build
    zero_kernel<<<(2 * NN + 255) / 256, 256, 0, stream>>>(counts, 2 * NN);
    hist_kernel<<<(NE + 255) / 256, 256, 0, stream>>>(dst, counts, NE);
    scan_kernel<<<1, 1024, 0, stream>>>(counts, row_ptr, NN);
    fill_kernel<<<(NE + 255) / 256, 256, 0, stream>>>(src, dst, row_ptr, cursor, csr, NE);

    // pre-split weights (once) and x0 -> XP0
    split_rows<<<DD, 256, 0, stream>>>(W1, W1P, PSW2, DD);
    split_rows<<<DD, 256, 0, stream>>>(W2, W2P, PSW2, DD);
    split_rows<<<3 * DD, 256, 0, stream>>>(Wih, WIHP, PSW3, 3 * DD);
    split_rows<<<3 * DD, 256, 0, stream>>>(Whh, WHHP, PSW3, 3 * DD);
    split_rows<<<NNP, 256, 0, stream>>>(x0, XP0, PSA, NN);

    const dim3 gridGRU(NNP / 128, 2);   // 391 x 2, 512-thread blocks

    for (int s = 0; s < NSTEPS; ++s) {
        u16* XPc = (s & 1) ? XP1 : XP0;
        u16* XPn = (s & 1) ? XP0 : XP1;

        // h = MLP(x) -> HP (single fp16 plane)
        mlp_fused<<<NNP / 32, 256, 0, stream>>>(
            XPc, W1P, W2P, PSW2, b1, b2, HP, NN);
        // msg = segment_sum(h[src], dst) -> TP (single fp16 plane)
        segsum_kernel<<<dim3((NN + 3) / 4), dim3(64, 4), 0, stream>>>(
            HP, row_ptr, csr, TP, NN);
        // full GRU update -> x_next planes (final: fp32 d_out)
        if (s < NSTEPS - 1) {
            gru_fused<false><<<gridGRU, 512, 0, stream>>>(
                TP, XPc, PSA, WIHP, WHHP, PSW3, bih, bhh,
                nullptr, XPn, PSA, NN);
        } else {
            gru_fused<true><<<gridGRU, 512, 0, stream>>>(
                TP, XPc, PSA, WIHP, WHHP, PSW3, bih, bhh,
                FOUT, nullptr, 0, NN);
        }
    }
}

// Round 18
// 1697.693 us; speedup vs baseline: 2.7019x; 1.1789x over previous
//
#include <hip/hip_runtime.h>
#include <hip/hip_bf16.h>
#include <math.h>

// Problem constants
#define NN 50000
#define NNP 50048       // rows padded to multiple of 128
#define NE 800000
#define DD 256
#define NSTEPS 6

#define BK 32

typedef unsigned short u16;
typedef _Float16 f16x8 __attribute__((ext_vector_type(8)));
typedef _Float16 f16x4 __attribute__((ext_vector_type(4)));
typedef float f32x4 __attribute__((ext_vector_type(4)));

__device__ __forceinline__ float sigmoidf_(float v) {
    return 1.0f / (1.0f + expf(-v));
}
__device__ __forceinline__ u16 f2h(float v) {
    _Float16 h = (_Float16)v;            // RNE
    u16 u; __builtin_memcpy(&u, &h, 2); return u;
}
__device__ __forceinline__ float h2f(u16 u) {
    _Float16 h; __builtin_memcpy(&h, &u, 2); return (float)h;
}
// fp16 2-way split: v ~= h + l to 2^-22 relative
__device__ __forceinline__ void split2(float v, u16& h, u16& l) {
    h = f2h(v);
    float r = v - h2f(h);
    l = f2h(r);
}
__device__ __forceinline__ unsigned pk(u16 a, u16 b) {
    return (unsigned)a | ((unsigned)b << 16);
}
__device__ __forceinline__ void store_planes(u16* base, size_t ps, size_t off, float v) {
    u16 h, l; split2(v, h, l);
    base[off] = h; base[ps + off] = l;
}
__device__ __forceinline__ void gload16(const void* g, void* l) {
    __builtin_amdgcn_global_load_lds(
        (const __attribute__((address_space(1))) void*)g,
        (__attribute__((address_space(3))) void*)l, 16, 0, 0);
}

// ---------------- CSR build (verified R1-R17) ----------------

__global__ void zero_kernel(int* __restrict__ p, int n) {
    int i = blockIdx.x * blockDim.x + threadIdx.x;
    if (i < n) p[i] = 0;
}
__global__ void hist_kernel(const int* __restrict__ dst, int* __restrict__ counts, int E) {
    int e = blockIdx.x * blockDim.x + threadIdx.x;
    if (e < E) atomicAdd(&counts[dst[e]], 1);
}
__global__ void scan_kernel(const int* __restrict__ counts, int* __restrict__ row_ptr, int n) {
    __shared__ int buf[1024];
    __shared__ int carry;
    const int tid = threadIdx.x;
    if (tid == 0) carry = 0;
    __syncthreads();
    for (int base = 0; base < n; base += 1024) {
        int i = base + tid;
        int v = (i < n) ? counts[i] : 0;
        buf[tid] = v;
        __syncthreads();
        for (int off = 1; off < 1024; off <<= 1) {
            int t = (tid >= off) ? buf[tid - off] : 0;
            __syncthreads();
            buf[tid] += t;
            __syncthreads();
        }
        if (i < n) row_ptr[i] = carry + buf[tid] - v;
        __syncthreads();
        if (tid == 0) carry += buf[1023];
        __syncthreads();
    }
    if (threadIdx.x == 0) row_ptr[n] = carry;
}
__global__ void fill_kernel(const int* __restrict__ src, const int* __restrict__ dst,
                            const int* __restrict__ row_ptr, int* __restrict__ cursor,
                            int* __restrict__ csr_src, int E) {
    int e = blockIdx.x * blockDim.x + threadIdx.x;
    if (e < E) {
        int d = dst[e];
        int p = atomicAdd(&cursor[d], 1);
        csr_src[row_ptr[d] + p] = src[e];
    }
}

// ---------------- fp32 -> 2 fp16 planes (rows padded w/ zero) ----------------
__global__ void split_rows(const float* __restrict__ src, u16* __restrict__ dst,
                           size_t pstride, int srcRows) {
    int row = blockIdx.x;
    int col = threadIdx.x;
    size_t off = (size_t)row * DD + col;
    float v = (row < srcRows) ? src[off] : 0.0f;
    store_planes(dst, pstride, off, v);
}

// ---------------- fp32 -> single fp16 plane ----------------
__global__ void half_rows(const float* __restrict__ src, u16* __restrict__ dst) {
    int row = blockIdx.x;
    int col = threadIdx.x;
    size_t off = (size_t)row * DD + col;
    dst[off] = f2h(src[off]);
}

// ---------------- fused MLP, 1-term products ----------------
// t1 = ReLU(xh @ W1h^T + b1) [fp16 in LDS]; h = t1 @ W2h^T + b2 -> fp16 HP.
// Weights hi-plane only: W staging 16 KB/k-iter (halved), MFMA halved.
__global__ __launch_bounds__(256, 3)
void mlp_fused(const u16* __restrict__ pX,
               const u16* __restrict__ W1H, const u16* __restrict__ W2H,
               const float* __restrict__ b1, const float* __restrict__ b2,
               u16* __restrict__ HP, int M) {
    // LDS (u16): A_h 2 subtiles @0 (1024); W 16 subtiles @1024 (8192);
    // t1 [32][256] swizzled @9216 (8192). Total 17408 u16 = 34.8 KB.
    __shared__ u16 lds[17408];
    const int T1B = 9216;

    const int tid = threadIdx.x;
    const int lane = tid & 63;
    const int wv = tid >> 6;           // col quarter 0..3
    const int frow = lane & 15;
    const int kg = lane >> 4;
    const int rowBase = blockIdx.x * 32;

    // staging: 18 x 1KB issues per k-iter, up to 5 per wave.
    int offj[5]; int ldsj[5]; bool isWj[5]; bool actj[5];
#pragma unroll
    for (int j = 0; j < 5; ++j) {
        int q = wv * 5 + j;
        actj[j] = q < 18;
        bool isW = q >= 2;
        int row, ldso, eoff = 0;
        if (q < 2) {
            row = q * 16 + (lane >> 2);
            int chunk = (lane & 3) ^ ((row >> 1) & 3);
            eoff = (rowBase + row) * DD + chunk * 8;
            ldso = q * 512;
        } else {
            int qw = (q - 2) & 15;
            row = qw * 16 + (lane >> 2);
            int chunk = (lane & 3) ^ ((row >> 1) & 3);
            eoff = row * DD + chunk * 8;
            ldso = 1024 + qw * 512;
        }
        offj[j] = eoff; ldsj[j] = ldso; isWj[j] = isW;
    }

    // phase 1: t1 = ReLU(xh @ W1h^T + b1)
    f32x4 acc1[2][4] = {};
    for (int kc = 0; kc < DD; kc += BK) {
#pragma unroll
        for (int j = 0; j < 5; ++j)
            if (actj[j]) gload16((isWj[j] ? W1H : pX) + offj[j] + kc, &lds[ldsj[j]]);
        __syncthreads();

        f16x8 af[2];
#pragma unroll
        for (int mf = 0; mf < 2; ++mf) {
            int row = mf * 16 + frow;
            af[mf] = *reinterpret_cast<const f16x8*>(
                &lds[row * 32 + ((kg ^ ((row >> 1) & 3)) * 8)]);
        }
#pragma unroll
        for (int nf = 0; nf < 4; ++nf) {
            int brow = wv * 64 + nf * 16 + frow;
            int boff = 1024 + brow * 32 + ((kg ^ ((brow >> 1) & 3)) * 8);
            f16x8 bh = *reinterpret_cast<const f16x8*>(&lds[boff]);
#pragma unroll
            for (int mf = 0; mf < 2; ++mf)
                acc1[mf][nf] = __builtin_amdgcn_mfma_f32_16x16x32_f16(
                    af[mf], bh, acc1[mf][nf], 0, 0, 0);
        }
        __syncthreads();
    }

    // t1 -> LDS fp16 (swizzled: chunk index XOR (row&7))
#pragma unroll
    for (int nf = 0; nf < 4; ++nf) {
        int col = wv * 64 + nf * 16 + frow;
        float bb = b1[col];
        int c8 = col >> 3, ci = col & 7;
#pragma unroll
        for (int mf = 0; mf < 2; ++mf) {
#pragma unroll
            for (int j = 0; j < 4; ++j) {
                int row = mf * 16 + kg * 4 + j;
                float v = fmaxf(acc1[mf][nf][j] + bb, 0.0f);
                lds[T1B + row * 256 + ((c8 ^ (row & 7)) * 8) + ci] = f2h(v);
            }
        }
    }
    __syncthreads();

    // phase 2: h = t1 @ W2h^T + b2 (1-term)
    f32x4 acc2[2][4] = {};
    for (int kc = 0; kc < DD; kc += BK) {
#pragma unroll
        for (int j = 0; j < 5; ++j)
            if (actj[j] && isWj[j]) gload16(W2H + offj[j] + kc, &lds[ldsj[j]]);
        __syncthreads();

        f16x8 at[2];
#pragma unroll
        for (int mf = 0; mf < 2; ++mf) {
            int row = mf * 16 + frow;
            int qc = (kc >> 3) + kg;
            at[mf] = *reinterpret_cast<const f16x8*>(
                &lds[T1B + row * 256 + ((qc ^ (row & 7)) * 8)]);
        }
#pragma unroll
        for (int nf = 0; nf < 4; ++nf) {
            int brow = wv * 64 + nf * 16 + frow;
            int boff = 1024 + brow * 32 + ((kg ^ ((brow >> 1) & 3)) * 8);
            f16x8 bh = *reinterpret_cast<const f16x8*>(&lds[boff]);
#pragma unroll
            for (int mf = 0; mf < 2; ++mf)
                acc2[mf][nf] = __builtin_amdgcn_mfma_f32_16x16x32_f16(
                    at[mf], bh, acc2[mf][nf], 0, 0, 0);
        }
        __syncthreads();
    }

#pragma unroll
    for (int nf = 0; nf < 4; ++nf) {
        int col = wv * 64 + nf * 16 + frow;
        float bb = b2[col];
#pragma unroll
        for (int mf = 0; mf < 2; ++mf) {
#pragma unroll
            for (int j = 0; j < 4; ++j) {
                int gr = rowBase + mf * 16 + kg * 4 + j;
                if (gr < M) HP[(size_t)gr * DD + col] = f2h(acc2[mf][nf][j] + bb);
            }
        }
    }
}

// ---------------- fused GRU: all gates 1-term, 2-subtile k-iter ----------------
// r = ah*Brh, z = ah*Bzh, n = ah*Bnh (each 1 MFMA) -> 24 MFMA/wave/k-iter.
// Gate injections ~2^-11 (R14/R16-validated class). x carry stays 2-plane.
// LDS 64 KB (2 subtiles x {A_h, r-hi, z-hi, n-hi}); 512 thr, 2 blocks/CU.
template <bool FINAL>
__global__ __launch_bounds__(512, 2)
void gru_fused(const u16* __restrict__ pMsgH, const u16* __restrict__ pX, size_t psA,
               const u16* __restrict__ pWihH, const u16* __restrict__ pWhhH,
               const float* __restrict__ bih, const float* __restrict__ bhh,
               float* __restrict__ outF, u16* __restrict__ outP, size_t psO, int M) {
    // Per k-subtile (16384 u16): A_h [128][32] @0; B panels @4096+g*4096 (r,z,n hi).
    // Two subtiles -> 32768 u16 = 64 KB.
    __shared__ u16 lds[32768];

    const int tid = threadIdx.x;
    const int lane = tid & 63;
    const int wv = tid >> 6;           // 0..7
    const int wr = wv >> 2;            // 0..1 (64-row half)
    const int wc = wv & 3;             // 0..3 (32-col quarter)
    const int frow = lane & 15;
    const int kg = lane >> 4;
    const int rowBase = blockIdx.x * 128;
    const int colBase = blockIdx.y * 128;

    // staging per subtile: 32 x 1KB issues, 4 per wave.
    // q = wv*4+j; q<8: A sub q; q>=8: qb=q-8 (0..23): gate qb>>3, sub qb&7.
    int offj[4]; int ldsj[4]; bool isBj[4];
#pragma unroll
    for (int j = 0; j < 4; ++j) {
        int q = wv * 4 + j;
        bool isB = q >= 8;
        int eoff, ldso;
        if (!isB) {
            int row = q * 16 + (lane >> 2);
            int chunk = (lane & 3) ^ ((row >> 1) & 3);
            eoff = (rowBase + row) * DD + chunk * 8;
            ldso = q * 512;
        } else {
            int qb = q - 8;                  // 0..23
            int gate = qb >> 3;              // 0:r 1:z 2:n
            int sub = qb & 7;
            int row = sub * 16 + (lane >> 2);
            int chunk = (lane & 3) ^ ((row >> 1) & 3);
            eoff = (gate * 256 + colBase + row) * DD + chunk * 8;
            ldso = 4096 + qb * 512;
        }
        offj[j] = eoff; ldsj[j] = ldso; isBj[j] = isB;
    }

    f32x4 accr[4][2] = {};
    f32x4 accz[4][2] = {};
    f32x4 accx[4][2] = {};
    f32x4 acch[4][2] = {};

#pragma unroll
    for (int half = 0; half < 2; ++half) {
        const u16* Ab = half ? pX : pMsgH;     // hi plane only
        const u16* Bb = half ? pWhhH : pWihH;  // hi plane only
        for (int kc = 0; kc < DD; kc += 2 * BK) {
#pragma unroll
            for (int j = 0; j < 4; ++j)
                gload16((isBj[j] ? Bb : Ab) + offj[j] + kc, &lds[ldsj[j]]);
#pragma unroll
            for (int j = 0; j < 4; ++j)
                gload16((isBj[j] ? Bb : Ab) + offj[j] + kc + BK, &lds[16384 + ldsj[j]]);
            __syncthreads();

#pragma unroll
            for (int st = 0; st < 2; ++st) {
                const u16* L = &lds[st * 16384];
                f16x8 af[4];
#pragma unroll
                for (int mf = 0; mf < 4; ++mf) {
                    int row = wr * 64 + mf * 16 + frow;
                    af[mf] = *reinterpret_cast<const f16x8*>(
                        &L[row * 32 + ((kg ^ ((row >> 1) & 3)) * 8)]);
                }
#pragma unroll
                for (int nf = 0; nf < 2; ++nf) {
                    int brow = wc * 32 + nf * 16 + frow;
                    int bsw = brow * 32 + ((kg ^ ((brow >> 1) & 3)) * 8);
                    f16x8 brh = *reinterpret_cast<const f16x8*>(&L[4096 + bsw]);
                    f16x8 bzh = *reinterpret_cast<const f16x8*>(&L[8192 + bsw]);
                    f16x8 bnh = *reinterpret_cast<const f16x8*>(&L[12288 + bsw]);
#pragma unroll
                    for (int mf = 0; mf < 4; ++mf) {
                        accr[mf][nf] = __builtin_amdgcn_mfma_f32_16x16x32_f16(
                            af[mf], brh, accr[mf][nf], 0, 0, 0);
                        accz[mf][nf] = __builtin_amdgcn_mfma_f32_16x16x32_f16(
                            af[mf], bzh, accz[mf][nf], 0, 0, 0);
                        f32x4 cn = (half == 0) ? accx[mf][nf] : acch[mf][nf];
                        cn = __builtin_amdgcn_mfma_f32_16x16x32_f16(af[mf], bnh, cn, 0, 0, 0);
                        if (half == 0) accx[mf][nf] = cn; else acch[mf][nf] = cn;
                    }
                }
            }
            __syncthreads();
        }
    }

    // epilogue: full GRU update (x blend uses both planes — full precision carry)
#pragma unroll
    for (int nf = 0; nf < 2; ++nf) {
        int gc = colBase + wc * 32 + nf * 16 + frow;
        float br = bih[gc] + bhh[gc];
        float bz = bih[256 + gc] + bhh[256 + gc];
        float bx = bih[512 + gc];
        float bh = bhh[512 + gc];
#pragma unroll
        for (int mf = 0; mf < 4; ++mf) {
#pragma unroll
            for (int j = 0; j < 4; ++j) {
                int gr = rowBase + wr * 64 + mf * 16 + kg * 4 + j;
                if (gr < M) {
                    size_t off = (size_t)gr * DD + gc;
                    float r = sigmoidf_(accr[mf][nf][j] + br);
                    float z = sigmoidf_(accz[mf][nf][j] + bz);
                    float T = tanhf(accx[mf][nf][j] + bx + r * (acch[mf][nf][j] + bh));
                    float x = h2f(pX[off]) + h2f(pX[psA + off]);
                    float o = (1.0f - z) * T + z * x;
                    if (FINAL) outF[off] = o;
                    else       store_planes(outP, psO, off, o);
                }
            }
        }
    }
}

// ---------------- segment sum -> msg single fp16 plane ----------------
__global__ __launch_bounds__(256)
void segsum_kernel(const u16* __restrict__ hp, const int* __restrict__ row_ptr,
                   const int* __restrict__ csr_src, u16* __restrict__ msgH, int n) {
    int node = blockIdx.x * 4 + threadIdx.y;
    if (node >= n) return;
    int d4 = threadIdx.x * 4;
    int s = row_ptr[node];
    int e = row_ptr[node + 1];
    float4 acc = make_float4(0.f, 0.f, 0.f, 0.f);
    for (int j = s; j < e; ++j) {
        int sn = csr_src[j];
        f16x4 v = *reinterpret_cast<const f16x4*>(&hp[(size_t)sn * DD + d4]);
        acc.x += (float)v[0]; acc.y += (float)v[1];
        acc.z += (float)v[2]; acc.w += (float)v[3];
    }
    size_t off = (size_t)node * DD + d4;
    *reinterpret_cast<uint2*>(&msgH[off]) =
        make_uint2(pk(f2h(acc.x), f2h(acc.y)), pk(f2h(acc.z), f2h(acc.w)));
}

// ---------------- launch ----------------

extern "C" void kernel_launch(void* const* d_in, const int* in_sizes, int n_in,
                              void* d_out, int out_size, void* d_ws, size_t ws_size,
                              hipStream_t stream) {
    const float* x0  = (const float*)d_in[0];
    const float* W1  = (const float*)d_in[1];
    const float* b1  = (const float*)d_in[2];
    const float* W2  = (const float*)d_in[3];
    const float* b2  = (const float*)d_in[4];
    const float* Wih = (const float*)d_in[5];
    const float* bih = (const float*)d_in[6];
    const float* Whh = (const float*)d_in[7];
    const float* bhh = (const float*)d_in[8];
    const int*   src = (const int*)d_in[9];
    const int*   dst = (const int*)d_in[10];

    // workspace layout (<= proven 211.3 MB footprint)
    char* ws = (char*)d_ws;
    const size_t PSA = (size_t)NNP * DD;
    const size_t SP  = PSA * 2 * sizeof(u16);
    const size_t NB  = PSA * sizeof(float);
    const size_t PSW2 = (size_t)DD * DD;
    const size_t PSW3 = (size_t)3 * DD * DD;
    u16* XP0   = (u16*)(ws);
    u16* XP1   = (u16*)(ws + SP);
    u16* TP    = (u16*)(ws + 2 * SP);       // msg single fp16 plane
    u16* HP    = (u16*)(ws + 3 * SP);       // h single fp16 plane
    u16* W1H   = (u16*)(ws + 3 * SP + NB);  // hi-plane-only weights
    u16* W2H   = W1H + PSW2;
    u16* WIHH  = W2H + PSW2;
    u16* WHHH  = WIHH + PSW3;
    int* counts  = (int*)(WHHH + PSW3);
    int* cursor  = counts + NN;
    int* row_ptr = cursor + NN;
    int* csr     = row_ptr + NN + 8;
    const size_t needed = 3 * SP + NB + (2 * PSW2 + 2 * PSW3) * sizeof(u16)
                        + (size_t)(2 * NN + NN + 9 + NE) * sizeof(int);
    if (ws_size < needed) return;

    float* FOUT = (float*)d_out;

    // CSR build
    zero_kernel<<<(2 * NN + 255) / 256, 256, 0, stream>>>(counts, 2 * NN);
    hist_kernel<<<(NE + 255) / 256, 256, 0, stream>>>(dst, counts, NE);
    scan_kernel<<<1, 1024, 0, stream>>>(counts, row_ptr, NN);
    fill_kernel<<<(NE + 255) / 256, 256, 0, stream>>>(src, dst, row_ptr, cursor, csr, NE);

    // weights: hi plane only; x0: 2-plane split
    half_rows<<<DD, 256, 0, stream>>>(W1, W1H);
    half_rows<<<DD, 256, 0, stream>>>(W2, W2H);
    half_rows<<<3 * DD, 256, 0, stream>>>(Wih, WIHH);
    half_rows<<<3 * DD, 256, 0, stream>>>(Whh, WHHH);
    split_rows<<<NNP, 256, 0, stream>>>(x0, XP0, PSA, NN);

    const dim3 gridGRU(NNP / 128, 2);   // 391 x 2, 512-thread blocks

    for (int s = 0; s < NSTEPS; ++s) {
        u16* XPc = (s & 1) ? XP1 : XP0;
        u16* XPn = (s & 1) ? XP0 : XP1;

        // h = MLP(x) -> HP (single fp16 plane)
        mlp_fused<<<NNP / 32, 256, 0, stream>>>(
            XPc, W1H, W2H, b1, b2, HP, NN);
        // msg = segment_sum(h[src], dst) -> TP (single fp16 plane)
        segsum_kernel<<<dim3((NN + 3) / 4), dim3(64, 4), 0, stream>>>(
            HP, row_ptr, csr, TP, NN);
        // full GRU update -> x_next planes (final: fp32 d_out)
        if (s < NSTEPS - 1) {
            gru_fused<false><<<gridGRU, 512, 0, stream>>>(
                TP, XPc, PSA, WIHH, WHHH, bih, bhh,
                nullptr, XPn, PSA, NN);
        } else {
            gru_fused<true><<<gridGRU, 512, 0, stream>>>(
                TP, XPc, PSA, WIHH, WHHH, bih, bhh,
                FOUT, nullptr, 0, NN);
        }
    }
}